// Round 7
// baseline (177.719 us; speedup 1.0000x reference)
//
#include <hip/hip_runtime.h>
#include <cstdint>

typedef __bf16 bf16_t;
typedef __bf16 bf16x4 __attribute__((ext_vector_type(4)));
typedef __bf16 bf16x8 __attribute__((ext_vector_type(8)));
typedef float floatx4 __attribute__((ext_vector_type(4)));

#define EMBED 1024
#define NHEAD 16
#define HDIM  64
#define SEQ   2048
#define BATCH 2
#define MTOT  (BATCH*SEQ)   /* 4096 */
// Q is pre-scaled by 1/sqrt(64) * log2(e) so softmax can use exp2
#define QSCALE 0.18033688011112042f

// async global->LDS, 16B per lane; LDS dest = wave-uniform base + lane*16
__device__ __forceinline__ void gload16(const bf16_t* g, bf16_t* l) {
    __builtin_amdgcn_global_load_lds(
        (const __attribute__((address_space(1))) void*)g,
        (__attribute__((address_space(3))) void*)l, 16, 0, 0);
}

// Explicit drain of the wave's own outstanding LDS-DMA (global_load_lds is
// tracked in vmcnt). __syncthreads() alone is NOT guaranteed to emit
// vmcnt(0) before s_barrier for LDS-DMA ops on every compiler build; the
// 1-deep double-buffer protocol is racy without it (warm-replay failures).
__device__ __forceinline__ void drain_dma() {
    asm volatile("s_waitcnt vmcnt(0)" ::: "memory");
}

// ---------------------------------------------------------------------------
// z<4 : transpose fp32 weight z into bf16 [n][k] (W^T)
// z>=4: straight convert slab z-4 of x fp32 -> bf16
// (R5 version -- R6's rewrite was part of an unattributed regression)
// ---------------------------------------------------------------------------
__global__ __launch_bounds__(256) void transpose4(
    const float* __restrict__ w0, const float* __restrict__ w1,
    const float* __restrict__ w2, const float* __restrict__ w3,
    const float* __restrict__ xin,
    bf16_t* __restrict__ out, bf16_t* __restrict__ xout)
{
    int z = blockIdx.z;
    int tx = threadIdx.x, ty = threadIdx.y;   // block (32,8)
    if (z >= 4) {
        const float* src = xin  + (size_t)(z - 4) * 1048576u;
        bf16_t*      dst = xout + (size_t)(z - 4) * 1048576u;
        int col = blockIdx.x * 32 + tx, rowb = blockIdx.y * 32;
#pragma unroll
        for (int j = 0; j < 4; j++) {
            int rr = rowb + ty + 8 * j;
            dst[(size_t)rr * 1024 + col] = (bf16_t)src[(size_t)rr * 1024 + col];
        }
        return;
    }
    __shared__ float t[32][33];
    const float* src = (z == 0) ? w0 : (z == 1) ? w1 : (z == 2) ? w2 : w3;
    bf16_t* dst = out + (size_t)z * 1048576u;
    int bx = blockIdx.x * 32, by = blockIdx.y * 32;
#pragma unroll
    for (int j = 0; j < 4; j++)
        t[ty + 8 * j][tx] = src[(size_t)(by + ty + 8 * j) * EMBED + bx + tx];
    __syncthreads();
#pragma unroll
    for (int j = 0; j < 4; j++)
        dst[(size_t)(bx + ty + 8 * j) * EMBED + by + tx] = (bf16_t)t[tx][ty + 8 * j];
}

// ---------------------------------------------------------------------------
// MFMA GEMM v2: global_load_lds DMA staging + LDS DOUBLE-BUFFER + one barrier
// per K-iter. The barrier at iter t drains the DMA issued at iter t-1
// (explicit vmcnt(0)). XOR chunk swizzle via the DMA source address.
// 1-D grid, XCD swizzle: block id%8 selects the m-group (R5 decode).
// MODE 0: fp32 out row-major.
// MODE 1: fused QKV. Q/K tiles (n0<2048) scatter to bf16 [b,h,s,d] (Q scaled
//         by QSCALE). V tiles (n0>=2048) transpose through LDS and write
//         Vt [b,h,d,s'] with the PV-operand key permutation folded in.
// ---------------------------------------------------------------------------
template<int BM, int MODE>
__global__ __launch_bounds__(256) void gemm_t(
    const bf16_t* __restrict__ A,  const bf16_t* __restrict__ Bt,
    const float* __restrict__ bias0, const float* __restrict__ bias1,
    const float* __restrict__ bias2,
    void* __restrict__ outraw, bf16_t* __restrict__ vtout,
    int M, int N, int K)
{
    constexpr int MS = BM / 32;          // m-subtiles per wave
    constexpr int BUFSZ = (BM + 128) * 64;
    __shared__ __align__(16) bf16_t smem[2 * BUFSZ];

    int tid  = threadIdx.x;
    // XCD-aware decode: id%8 = m-group -> same-XCD blocks share A rows
    int id   = blockIdx.x;
    int c8   = id & 7, rr_ = id >> 3;
    int nblk = N >> 7;
    int n0   = (rr_ % nblk) * 128;
    int m0   = ((rr_ / nblk) * 8 + c8) * BM;
    int wv   = tid >> 6, lane = tid & 63;
    int wr   = wv >> 1,  wc   = wv & 1;
    int quad = lane >> 4, l16 = lane & 15;
    int lr   = lane >> 3, lq = lane & 7;
    int sw   = (l16 & 7) * 8;                    // reader swizzle (elems)
    int lcs  = ((lq ^ lr) * 8);                  // DMA source chunk (elems)

    floatx4 acc[MS][4];
    floatx4 z4 = {0.f, 0.f, 0.f, 0.f};
#pragma unroll
    for (int mi = 0; mi < MS; mi++)
#pragma unroll
        for (int ni = 0; ni < 4; ni++) acc[mi][ni] = z4;

    auto STAGE = [&](int k0, int buf) {
        bf16_t* as = smem + buf * BUFSZ;
        bf16_t* bs = as + BM * 64;
#pragma unroll
        for (int i = 0; i < BM / 32; i++) {
            int r = wv * (BM / 4) + i * 8;
            gload16(&A[(size_t)(m0 + r + lr) * K + k0 + lcs], as + r * 64);
        }
#pragma unroll
        for (int i = 0; i < 4; i++) {
            int r = wv * 32 + i * 8;
            gload16(&Bt[(size_t)(n0 + r + lr) * K + k0 + lcs], bs + r * 64);
        }
    };

    STAGE(0, 0);
    int T = K >> 6;
    for (int t = 0; t < T; t++) {
        int cur = t & 1;
        drain_dma();                     // own DMA (incl. prefetch) complete
        __syncthreads();                 // buf[cur] DMA complete (1-tile cover)
        if (t + 1 < T) STAGE((t + 1) << 6, cur ^ 1);
        bf16_t (*As)[64] = (bf16_t(*)[64])(smem + cur * BUFSZ);
        bf16_t (*Bs)[64] = (bf16_t(*)[64])(smem + cur * BUFSZ + BM * 64);
#pragma unroll
        for (int kk = 0; kk < 2; kk++) {
            bf16x8 af[MS], bfr[4];
            int co = kk * 32 + quad * 8;
#pragma unroll
            for (int i = 0; i < MS; i++)
                af[i]  = *(const bf16x8*)&As[wr * (BM / 2) + i * 16 + l16][co ^ sw];
#pragma unroll
            for (int i = 0; i < 4; i++)
                bfr[i] = *(const bf16x8*)&Bs[wc * 64 + i * 16 + l16][co ^ sw];
#pragma unroll
            for (int mi = 0; mi < MS; mi++)
#pragma unroll
                for (int ni = 0; ni < 4; ni++)
                    acc[mi][ni] = __builtin_amdgcn_mfma_f32_16x16x32_bf16(
                        af[mi], bfr[ni], acc[mi][ni], 0, 0, 0);
        }
    }

    if constexpr (MODE == 1) {
        if (n0 >= 2048) {
            // ------- V tile: LDS transpose + permuted coalesced Vt write ----
            bf16_t (*Ts)[72] = (bf16_t(*)[72])smem;   // 128 hd x 64 s' (+pad)
            int bb = m0 >> 11, s0 = m0 & 2047;
            int hd0 = n0 & 1023;
#pragma unroll
            for (int mh = 0; mh < 2; mh++) {
                __syncthreads();
                if (wr == mh) {
#pragma unroll
                    for (int mi = 0; mi < MS; mi++)
#pragma unroll
                        for (int ni = 0; ni < 4; ni++)
#pragma unroll
                            for (int r = 0; r < 4; r++) {
                                int ml = mi * 16 + quad * 4 + r;     // 0..63
                                int nl = wc * 64 + ni * 16 + l16;    // 0..127
                                float v = acc[mi][ni][r] + bias2[hd0 + nl];
                                int sp = ((ml >> 5) << 5) | (((ml >> 2) & 3) << 3)
                                       | (((ml >> 4) & 1) << 2) | (ml & 3);
                                Ts[nl][sp] = (bf16_t)v;
                            }
                }
                __syncthreads();
#pragma unroll
                for (int i = 0; i < 4; i++) {
                    int c = tid + i * 256;          // 1024 chunk-writes
                    int row = c >> 3, ch = (c & 7) * 8;
                    int hh = row >> 6, dd = row & 63;
                    size_t off = (((size_t)bb * NHEAD + (hd0 >> 6) + hh) * HDIM + dd) * SEQ
                               + (size_t)(s0 + mh * 64 + ch);
                    *(bf16x8*)&vtout[off] = *(const bf16x8*)&Ts[row][ch];
                }
            }
            return;
        }
    }

    // epilogue: C/D layout col = lane&15 (n), row = quad*4 + reg (m)
#pragma unroll
    for (int mi = 0; mi < MS; mi++) {
#pragma unroll
        for (int ni = 0; ni < 4; ni++) {
            int n = n0 + wc * 64 + ni * 16 + l16;
#pragma unroll
            for (int r = 0; r < 4; r++) {
                int m = m0 + wr * (BM / 2) + mi * 16 + quad * 4 + r;
                float v = acc[mi][ni][r];
                if (MODE == 0) {
                    ((float*)outraw)[(size_t)m * N + n] = v + bias0[n];
                } else {
                    int which = n >> 10, cc = n & 1023;   // 0=Q, 1=K here
                    v += (which == 0) ? bias0[cc] : bias1[cc];
                    if (which == 0) v *= QSCALE;
                    int h = cc >> 6, d = cc & 63;
                    int b = m >> 11, s = m & 2047;
                    ((bf16_t*)outraw)[(size_t)which * 4194304u +
                        (((size_t)b * NHEAD + h) * SEQ + s) * HDIM + d] = (bf16_t)v;
                }
            }
        }
    }
}

// ---------------------------------------------------------------------------
// MFMA flash attention v7 (unchanged from R5 -- control):
// S^T-trick, KVBLK=128 (16 iters), V as two half-tiles Vs[buf][half][64][64]
// (verified conflict-free), l via ones-MFMA, half-split QK/SM/PV pipeline,
// DMA double-buffer + explicit vmcnt drain.
// ---------------------------------------------------------------------------
__global__ __launch_bounds__(512, 4) void attn_mfma(
    const bf16_t* __restrict__ Q, const bf16_t* __restrict__ K,
    const bf16_t* __restrict__ Vt, bf16_t* __restrict__ O)
{
    __shared__ __align__(16) bf16_t Ks[2][128][64];     // [buf][key][dim]
    __shared__ __align__(16) bf16_t Vs[2][2][64][64];   // [buf][half][dim][key]

    int tid  = threadIdx.x;
    int wv   = tid >> 6, lane = tid & 63;            // wv 0..7
    int quad = lane >> 4, l16 = lane & 15;
    int sw   = (l16 & 7) * 8;
    int lr8  = lane >> 3, lq8  = lane & 7;           // staging decomp
    int flat = blockIdx.x;
    int hb   = flat & 31;               // head-batch group; XCD = flat%8 = hb%8
    int qt   = flat >> 5;               // q-tile 0..15 (128 rows each)
    int h = hb & 15, b = hb >> 4;
    int bh = b * NHEAD + h;
    int qw = qt * 128 + wv * 16;        // wave's 16 query rows

    const bf16_t* Qb = Q  + (size_t)bh * SEQ * HDIM;
    const bf16_t* Kb = K  + (size_t)bh * SEQ * HDIM;
    const bf16_t* Vb = Vt + (size_t)bh * SEQ * HDIM;   // row d, col key'

    // staging: waves 0-3 -> K rows [wv*32, +32) (4 gload16).
    // waves 4-7 -> V half (w>>1), dims (w&1)*32 + [0..31] (4 gload16),
    // v4-style per-row chunk swizzle (lq8 ^ lr8).
    int vwave = wv >> 2;
    int w3    = wv & 3;
    const bf16_t* kgp = Kb + (size_t)(wv * 32 + lr8) * HDIM + (lq8 ^ lr8) * 8;
    int vhalf = w3 >> 1, vd0 = (w3 & 1) * 32;
    const bf16_t* vgp = Vb + (size_t)(vd0 + lr8) * SEQ + vhalf * 64
                           + (size_t)((lq8 ^ lr8) * 8);

    auto STAGE = [&](int t, int buf) {
        if (!vwave) {
            const bf16_t* g = kgp + (size_t)t * (128u * HDIM);
            bf16_t* l = &Ks[buf][wv * 32][0];
            gload16(g,             l);
            gload16(g +  8 * HDIM, l +  8 * 64);
            gload16(g + 16 * HDIM, l + 16 * 64);
            gload16(g + 24 * HDIM, l + 24 * 64);
        } else {
            const bf16_t* g = vgp + (size_t)t * 128u;
            bf16_t* l = &Vs[buf][vhalf][vd0][0];
            gload16(g,            l);
            gload16(g +  8 * SEQ, l +  8 * 64);
            gload16(g + 16 * SEQ, l + 16 * 64);
            gload16(g + 24 * SEQ, l + 24 * 64);
        }
    };

    // Q fragments (B-operand: n=q=l16, k=dims), registers for whole kernel
    bf16x8 qf[2];
#pragma unroll
    for (int kk = 0; kk < 2; kk++)
        qf[kk] = *(const bf16x8*)
            &Qb[(size_t)(qw + l16) * HDIM + kk * 32 + quad * 8];

    bf16x8 ones;
#pragma unroll
    for (int i = 0; i < 8; i++) ones[i] = (bf16_t)1.0f;

    floatx4 o_acc[4];
    floatx4 z4  = {0.f, 0.f, 0.f, 0.f};
    floatx4 m16 = {-16.f, -16.f, -16.f, -16.f};
#pragma unroll
    for (int nd = 0; nd < 4; nd++) o_acc[nd] = z4;
    floatx4 l_acc = z4;

    // prologue: stage tile 0 into buffer 0
    STAGE(0, 0);

    for (int t = 0; t < 16; t++) {
        int cur = t & 1;
        drain_dma();       // own DMA complete (incl. prefetch issued last iter)
        __syncthreads();   // buf[cur] fully staged by all waves
        if (t < 15) STAGE(t + 1, cur ^ 1);

        // S^T - 16 = K @ Q^T - 16 : D[key][q], col=l16=q, row=quad*4+r=key
        // half a: keys 0..63 -> st0; half b: keys 64..127 -> st1
        floatx4 st0[4], st1[4];
#pragma unroll
        for (int ns = 0; ns < 4; ns++) { st0[ns] = m16; st1[ns] = m16; }
        __builtin_amdgcn_s_setprio(1);
#pragma unroll
        for (int ns = 0; ns < 4; ns++)
#pragma unroll
            for (int kk = 0; kk < 2; kk++) {
                bf16x8 kf = *(const bf16x8*)
                    &Ks[cur][ns * 16 + l16][(kk * 32 + quad * 8) ^ sw];
                st0[ns] = __builtin_amdgcn_mfma_f32_16x16x32_bf16(
                    kf, qf[kk], st0[ns], 0, 0, 0);
            }
#pragma unroll
        for (int ns = 0; ns < 4; ns++)
#pragma unroll
            for (int kk = 0; kk < 2; kk++) {
                bf16x8 kf = *(const bf16x8*)
                    &Ks[cur][(ns + 4) * 16 + l16][(kk * 32 + quad * 8) ^ sw];
                st1[ns] = __builtin_amdgcn_mfma_f32_16x16x32_bf16(
                    kf, qf[kk], st1[ns], 0, 0, 0);
            }
        __builtin_amdgcn_s_setprio(0);

        // SM(a): P^T = exp2(S^T) keys 0..63, repacked as PV B-operand frags
        bf16x8 pf0[2];
#pragma unroll
        for (int kk = 0; kk < 2; kk++)
#pragma unroll
            for (int tt = 0; tt < 8; tt++)
                pf0[kk][tt] = (bf16_t)__builtin_amdgcn_exp2f(
                    st0[2 * kk + (tt >> 2)][tt & 3]);

        // PV(a): O^T += V^T @ P (keys 0..63); l via ones-MFMA
        __builtin_amdgcn_s_setprio(1);
#pragma unroll
        for (int nd = 0; nd < 4; nd++)
#pragma unroll
            for (int kk = 0; kk < 2; kk++) {
                bf16x8 vf = *(const bf16x8*)
                    &Vs[cur][0][nd * 16 + l16][(kk * 32 + quad * 8) ^ sw];
                o_acc[nd] = __builtin_amdgcn_mfma_f32_16x16x32_bf16(
                    vf, pf0[kk], o_acc[nd], 0, 0, 0);
            }
#pragma unroll
        for (int kk = 0; kk < 2; kk++)
            l_acc = __builtin_amdgcn_mfma_f32_16x16x32_bf16(
                ones, pf0[kk], l_acc, 0, 0, 0);
        __builtin_amdgcn_s_setprio(0);

        // SM(b): keys 64..127 (overlaps PV(a) on the trans/VALU pipes)
        bf16x8 pf1[2];
#pragma unroll
        for (int kk = 0; kk < 2; kk++)
#pragma unroll
            for (int tt = 0; tt < 8; tt++)
                pf1[kk][tt] = (bf16_t)__builtin_amdgcn_exp2f(
                    st1[2 * kk + (tt >> 2)][tt & 3]);

        // PV(b): keys 64..127 (V half 1)
        __builtin_amdgcn_s_setprio(1);
#pragma unroll
        for (int nd = 0; nd < 4; nd++)
#pragma unroll
            for (int kk = 0; kk < 2; kk++) {
                bf16x8 vf = *(const bf16x8*)
                    &Vs[cur][1][nd * 16 + l16][(kk * 32 + quad * 8) ^ sw];
                o_acc[nd] = __builtin_amdgcn_mfma_f32_16x16x32_bf16(
                    vf, pf1[kk], o_acc[nd], 0, 0, 0);
            }
#pragma unroll
        for (int kk = 0; kk < 2; kk++)
            l_acc = __builtin_amdgcn_mfma_f32_16x16x32_bf16(
                ones, pf1[kk], l_acc, 0, 0, 0);
        __builtin_amdgcn_s_setprio(0);
    }

    // l_acc: every reg r of every quad holds the complete l for q = l16.
    float inv = 1.f / l_acc[0];
    int q = qw + l16;
    bf16_t* ob = O + ((size_t)b * SEQ + q) * EMBED + h * HDIM;
#pragma unroll
    for (int nd = 0; nd < 4; nd++)
#pragma unroll
        for (int r = 0; r < 4; r++)
            ob[nd * 16 + quad * 4 + r] = (bf16_t)(o_acc[nd][r] * inv);
}

// ---------------------------------------------------------------------------
// Workspace layout (bytes):
//   [0,  8MB): W^T bf16 (4 x 1M)
//   [8, 16MB): x bf16 [4096,1024]
//   [16,40MB): Q,K bf16 [b,h,s,d] (Q scaled by QSCALE); V slot unused
//   [40,48MB): Vt bf16 [b,h,d,s'] (key-permuted per 64-block, PV-operand map)
//   [48,56MB): attention out bf16 [b,s,h*d]
// ---------------------------------------------------------------------------
extern "C" void kernel_launch(void* const* d_in, const int* in_sizes, int n_in,
                              void* d_out, int out_size, void* d_ws, size_t ws_size,
                              hipStream_t stream)
{
    const float* x  = (const float*)d_in[0];
    const float* wq = (const float*)d_in[1];
    const float* bq = (const float*)d_in[2];
    const float* wk = (const float*)d_in[3];
    const float* bk = (const float*)d_in[4];
    const float* wv = (const float*)d_in[5];
    const float* bv = (const float*)d_in[6];
    const float* wo = (const float*)d_in[7];
    const float* bo = (const float*)d_in[8];

    char*   ws    = (char*)d_ws;
    bf16_t* Wt    = (bf16_t*)ws;                           // 4 x 1048576 bf16
    bf16_t* Xb    = (bf16_t*)(ws + 8ull  * 1024 * 1024);   // 4194304 bf16
    bf16_t* QKV   = (bf16_t*)(ws + 16ull * 1024 * 1024);   // 3 x 4194304 bf16
    bf16_t* Vt    = (bf16_t*)(ws + 40ull * 1024 * 1024);   // 4194304 bf16
    bf16_t* attnO = (bf16_t*)(ws + 48ull * 1024 * 1024);   // 4194304 bf16
    float*  outp  = (float*)d_out;

    // weights transpose + x convert, one launch
    transpose4<<<dim3(32, 32, 8), dim3(32, 8), 0, stream>>>(
        wq, wk, wv, wo, x, Wt, Xb);

    // fused QKV projection: Q/K -> [b,h,s,d]; V -> Vt [b,h,d,s'] directly
    // 1-D grid 768: id%8 = m-group (A rows L2-local per XCD)  [R5 decode]
    gemm_t<128, 1><<<dim3(768), 256, 0, stream>>>(
        Xb, Wt, bq, bk, bv, QKV, Vt, MTOT, 3072, EMBED);

    attn_mfma<<<dim3(512), 512, 0, stream>>>(
        QKV, QKV + 4194304u, Vt, attnO);

    // output projection: [4096,1024] @ [1024,1024] -> d_out (fp32)
    // BM=128 tile (2.6x better MFMA density per ladder 64^2 vs 128^2),
    // grid 256 = 32 m-groups x 8 n-blocks, 1 block/CU
    gemm_t<128, 0><<<dim3(256), 256, 0, stream>>>(
        attnO, Wt + 3u * 1048576u, bo, bo, bo, outp, nullptr, MTOT, EMBED, EMBED);
}

// Round 8
// 176.659 us; speedup vs baseline: 1.0060x; 1.0060x over previous
//
#include <hip/hip_runtime.h>
#include <cstdint>

typedef __bf16 bf16_t;
typedef __bf16 bf16x4 __attribute__((ext_vector_type(4)));
typedef __bf16 bf16x8 __attribute__((ext_vector_type(8)));
typedef float floatx4 __attribute__((ext_vector_type(4)));

#define EMBED 1024
#define NHEAD 16
#define HDIM  64
#define SEQ   2048
#define BATCH 2
#define MTOT  (BATCH*SEQ)   /* 4096 */
// Q is pre-scaled by 1/sqrt(64) * log2(e) so softmax can use exp2
#define QSCALE 0.18033688011112042f

// async global->LDS, 16B per lane; LDS dest = wave-uniform base + lane*16
__device__ __forceinline__ void gload16(const bf16_t* g, bf16_t* l) {
    __builtin_amdgcn_global_load_lds(
        (const __attribute__((address_space(1))) void*)g,
        (__attribute__((address_space(3))) void*)l, 16, 0, 0);
}

// Explicit drain of the wave's own outstanding LDS-DMA (global_load_lds is
// tracked in vmcnt). __syncthreads() alone is NOT guaranteed to emit
// vmcnt(0) before s_barrier for LDS-DMA ops on every compiler build; the
// 1-deep double-buffer protocol is racy without it (warm-replay failures).
__device__ __forceinline__ void drain_dma() {
    asm volatile("s_waitcnt vmcnt(0)" ::: "memory");
}

// ---------------------------------------------------------------------------
// z<4 : transpose fp32 weight z into bf16 [n][k] (W^T)  [R5 path, untouched]
// z>=4: x fp32 -> bf16 convert, float4/bf16x4 vectorized (G13; the only
//       change vs R5 -- clean single-variable attribution this round)
// ---------------------------------------------------------------------------
__global__ __launch_bounds__(256) void transpose4(
    const float* __restrict__ w0, const float* __restrict__ w1,
    const float* __restrict__ w2, const float* __restrict__ w3,
    const float* __restrict__ xin,
    bf16_t* __restrict__ out, bf16_t* __restrict__ xout)
{
    int z = blockIdx.z;
    int tx = threadIdx.x, ty = threadIdx.y;   // block (32,8)
    if (z >= 4) {
        // x convert: 1024 blocks/slab x 256 thr x 1 float4 = 1M floats
        int flat = blockIdx.y * 32 + blockIdx.x;
        int t256 = ty * 32 + tx;
        size_t idx = (size_t)flat * 256 + t256;
        const floatx4* s4 = (const floatx4*)(xin + (size_t)(z - 4) * 1048576u);
        floatx4 v = s4[idx];
        bf16x4 o = { (bf16_t)v[0], (bf16_t)v[1], (bf16_t)v[2], (bf16_t)v[3] };
        ((bf16x4*)(xout + (size_t)(z - 4) * 1048576u))[idx] = o;
        return;
    }
    __shared__ float t[32][33];
    const float* src = (z == 0) ? w0 : (z == 1) ? w1 : (z == 2) ? w2 : w3;
    bf16_t* dst = out + (size_t)z * 1048576u;
    int bx = blockIdx.x * 32, by = blockIdx.y * 32;
#pragma unroll
    for (int j = 0; j < 4; j++)
        t[ty + 8 * j][tx] = src[(size_t)(by + ty + 8 * j) * EMBED + bx + tx];
    __syncthreads();
#pragma unroll
    for (int j = 0; j < 4; j++)
        dst[(size_t)(bx + ty + 8 * j) * EMBED + by + tx] = (bf16_t)t[tx][ty + 8 * j];
}

// ---------------------------------------------------------------------------
// MFMA GEMM v2 (R5): global_load_lds DMA staging + LDS DOUBLE-BUFFER + one
// barrier per K-iter (explicit vmcnt(0) drain). XOR chunk swizzle via the
// DMA source address. 1-D grid, XCD swizzle: id%8 = m-group.
// MODE 0: fp32 out row-major.
// MODE 1: fused QKV. Q/K tiles (n0<2048) scatter to bf16 [b,h,s,d] (Q scaled
//         by QSCALE). V tiles (n0>=2048) transpose through LDS and write
//         Vt [b,h,d,s'] with the PV-operand key permutation folded in.
// ---------------------------------------------------------------------------
template<int BM, int MODE>
__global__ __launch_bounds__(256) void gemm_t(
    const bf16_t* __restrict__ A,  const bf16_t* __restrict__ Bt,
    const float* __restrict__ bias0, const float* __restrict__ bias1,
    const float* __restrict__ bias2,
    void* __restrict__ outraw, bf16_t* __restrict__ vtout,
    int M, int N, int K)
{
    constexpr int MS = BM / 32;          // m-subtiles per wave
    constexpr int BUFSZ = (BM + 128) * 64;
    __shared__ __align__(16) bf16_t smem[2 * BUFSZ];

    int tid  = threadIdx.x;
    // XCD-aware decode: id%8 = m-group -> same-XCD blocks share A rows
    int id   = blockIdx.x;
    int c8   = id & 7, rr_ = id >> 3;
    int nblk = N >> 7;
    int n0   = (rr_ % nblk) * 128;
    int m0   = ((rr_ / nblk) * 8 + c8) * BM;
    int wv   = tid >> 6, lane = tid & 63;
    int wr   = wv >> 1,  wc   = wv & 1;
    int quad = lane >> 4, l16 = lane & 15;
    int lr   = lane >> 3, lq = lane & 7;
    int sw   = (l16 & 7) * 8;                    // reader swizzle (elems)
    int lcs  = ((lq ^ lr) * 8);                  // DMA source chunk (elems)

    floatx4 acc[MS][4];
    floatx4 z4 = {0.f, 0.f, 0.f, 0.f};
#pragma unroll
    for (int mi = 0; mi < MS; mi++)
#pragma unroll
        for (int ni = 0; ni < 4; ni++) acc[mi][ni] = z4;

    auto STAGE = [&](int k0, int buf) {
        bf16_t* as = smem + buf * BUFSZ;
        bf16_t* bs = as + BM * 64;
#pragma unroll
        for (int i = 0; i < BM / 32; i++) {
            int r = wv * (BM / 4) + i * 8;
            gload16(&A[(size_t)(m0 + r + lr) * K + k0 + lcs], as + r * 64);
        }
#pragma unroll
        for (int i = 0; i < 4; i++) {
            int r = wv * 32 + i * 8;
            gload16(&Bt[(size_t)(n0 + r + lr) * K + k0 + lcs], bs + r * 64);
        }
    };

    STAGE(0, 0);
    int T = K >> 6;
    for (int t = 0; t < T; t++) {
        int cur = t & 1;
        drain_dma();                     // own DMA (incl. prefetch) complete
        __syncthreads();                 // buf[cur] DMA complete (1-tile cover)
        if (t + 1 < T) STAGE((t + 1) << 6, cur ^ 1);
        bf16_t (*As)[64] = (bf16_t(*)[64])(smem + cur * BUFSZ);
        bf16_t (*Bs)[64] = (bf16_t(*)[64])(smem + cur * BUFSZ + BM * 64);
#pragma unroll
        for (int kk = 0; kk < 2; kk++) {
            bf16x8 af[MS], bfr[4];
            int co = kk * 32 + quad * 8;
#pragma unroll
            for (int i = 0; i < MS; i++)
                af[i]  = *(const bf16x8*)&As[wr * (BM / 2) + i * 16 + l16][co ^ sw];
#pragma unroll
            for (int i = 0; i < 4; i++)
                bfr[i] = *(const bf16x8*)&Bs[wc * 64 + i * 16 + l16][co ^ sw];
#pragma unroll
            for (int mi = 0; mi < MS; mi++)
#pragma unroll
                for (int ni = 0; ni < 4; ni++)
                    acc[mi][ni] = __builtin_amdgcn_mfma_f32_16x16x32_bf16(
                        af[mi], bfr[ni], acc[mi][ni], 0, 0, 0);
        }
    }

    if constexpr (MODE == 1) {
        if (n0 >= 2048) {
            // ------- V tile: LDS transpose + permuted coalesced Vt write ----
            bf16_t (*Ts)[72] = (bf16_t(*)[72])smem;   // 128 hd x 64 s' (+pad)
            int bb = m0 >> 11, s0 = m0 & 2047;
            int hd0 = n0 & 1023;
#pragma unroll
            for (int mh = 0; mh < 2; mh++) {
                __syncthreads();
                if (wr == mh) {
#pragma unroll
                    for (int mi = 0; mi < MS; mi++)
#pragma unroll
                        for (int ni = 0; ni < 4; ni++)
#pragma unroll
                            for (int r = 0; r < 4; r++) {
                                int ml = mi * 16 + quad * 4 + r;     // 0..63
                                int nl = wc * 64 + ni * 16 + l16;    // 0..127
                                float v = acc[mi][ni][r] + bias2[hd0 + nl];
                                int sp = ((ml >> 5) << 5) | (((ml >> 2) & 3) << 3)
                                       | (((ml >> 4) & 1) << 2) | (ml & 3);
                                Ts[nl][sp] = (bf16_t)v;
                            }
                }
                __syncthreads();
#pragma unroll
                for (int i = 0; i < 4; i++) {
                    int c = tid + i * 256;          // 1024 chunk-writes
                    int row = c >> 3, ch = (c & 7) * 8;
                    int hh = row >> 6, dd = row & 63;
                    size_t off = (((size_t)bb * NHEAD + (hd0 >> 6) + hh) * HDIM + dd) * SEQ
                               + (size_t)(s0 + mh * 64 + ch);
                    *(bf16x8*)&vtout[off] = *(const bf16x8*)&Ts[row][ch];
                }
            }
            return;
        }
    }

    // epilogue: C/D layout col = lane&15 (n), row = quad*4 + reg (m)
#pragma unroll
    for (int mi = 0; mi < MS; mi++) {
#pragma unroll
        for (int ni = 0; ni < 4; ni++) {
            int n = n0 + wc * 64 + ni * 16 + l16;
#pragma unroll
            for (int r = 0; r < 4; r++) {
                int m = m0 + wr * (BM / 2) + mi * 16 + quad * 4 + r;
                float v = acc[mi][ni][r];
                if (MODE == 0) {
                    ((float*)outraw)[(size_t)m * N + n] = v + bias0[n];
                } else {
                    int which = n >> 10, cc = n & 1023;   // 0=Q, 1=K here
                    v += (which == 0) ? bias0[cc] : bias1[cc];
                    if (which == 0) v *= QSCALE;
                    int h = cc >> 6, d = cc & 63;
                    int b = m >> 11, s = m & 2047;
                    ((bf16_t*)outraw)[(size_t)which * 4194304u +
                        (((size_t)b * NHEAD + h) * SEQ + s) * HDIM + d] = (bf16_t)v;
                }
            }
        }
    }
}

// ---------------------------------------------------------------------------
// MFMA flash attention v7 (unchanged from R5 -- control):
// S^T-trick, KVBLK=128 (16 iters), V as two half-tiles Vs[buf][half][64][64]
// (verified conflict-free), l via ones-MFMA, half-split QK/SM/PV pipeline,
// DMA double-buffer + explicit vmcnt drain.
// ---------------------------------------------------------------------------
__global__ __launch_bounds__(512, 4) void attn_mfma(
    const bf16_t* __restrict__ Q, const bf16_t* __restrict__ K,
    const bf16_t* __restrict__ Vt, bf16_t* __restrict__ O)
{
    __shared__ __align__(16) bf16_t Ks[2][128][64];     // [buf][key][dim]
    __shared__ __align__(16) bf16_t Vs[2][2][64][64];   // [buf][half][dim][key]

    int tid  = threadIdx.x;
    int wv   = tid >> 6, lane = tid & 63;            // wv 0..7
    int quad = lane >> 4, l16 = lane & 15;
    int sw   = (l16 & 7) * 8;
    int lr8  = lane >> 3, lq8  = lane & 7;           // staging decomp
    int flat = blockIdx.x;
    int hb   = flat & 31;               // head-batch group; XCD = flat%8 = hb%8
    int qt   = flat >> 5;               // q-tile 0..15 (128 rows each)
    int h = hb & 15, b = hb >> 4;
    int bh = b * NHEAD + h;
    int qw = qt * 128 + wv * 16;        // wave's 16 query rows

    const bf16_t* Qb = Q  + (size_t)bh * SEQ * HDIM;
    const bf16_t* Kb = K  + (size_t)bh * SEQ * HDIM;
    const bf16_t* Vb = Vt + (size_t)bh * SEQ * HDIM;   // row d, col key'

    // staging: waves 0-3 -> K rows [wv*32, +32) (4 gload16).
    // waves 4-7 -> V half (w>>1), dims (w&1)*32 + [0..31] (4 gload16),
    // v4-style per-row chunk swizzle (lq8 ^ lr8).
    int vwave = wv >> 2;
    int w3    = wv & 3;
    const bf16_t* kgp = Kb + (size_t)(wv * 32 + lr8) * HDIM + (lq8 ^ lr8) * 8;
    int vhalf = w3 >> 1, vd0 = (w3 & 1) * 32;
    const bf16_t* vgp = Vb + (size_t)(vd0 + lr8) * SEQ + vhalf * 64
                           + (size_t)((lq8 ^ lr8) * 8);

    auto STAGE = [&](int t, int buf) {
        if (!vwave) {
            const bf16_t* g = kgp + (size_t)t * (128u * HDIM);
            bf16_t* l = &Ks[buf][wv * 32][0];
            gload16(g,             l);
            gload16(g +  8 * HDIM, l +  8 * 64);
            gload16(g + 16 * HDIM, l + 16 * 64);
            gload16(g + 24 * HDIM, l + 24 * 64);
        } else {
            const bf16_t* g = vgp + (size_t)t * 128u;
            bf16_t* l = &Vs[buf][vhalf][vd0][0];
            gload16(g,            l);
            gload16(g +  8 * SEQ, l +  8 * 64);
            gload16(g + 16 * SEQ, l + 16 * 64);
            gload16(g + 24 * SEQ, l + 24 * 64);
        }
    };

    // Q fragments (B-operand: n=q=l16, k=dims), registers for whole kernel
    bf16x8 qf[2];
#pragma unroll
    for (int kk = 0; kk < 2; kk++)
        qf[kk] = *(const bf16x8*)
            &Qb[(size_t)(qw + l16) * HDIM + kk * 32 + quad * 8];

    bf16x8 ones;
#pragma unroll
    for (int i = 0; i < 8; i++) ones[i] = (bf16_t)1.0f;

    floatx4 o_acc[4];
    floatx4 z4  = {0.f, 0.f, 0.f, 0.f};
    floatx4 m16 = {-16.f, -16.f, -16.f, -16.f};
#pragma unroll
    for (int nd = 0; nd < 4; nd++) o_acc[nd] = z4;
    floatx4 l_acc = z4;

    // prologue: stage tile 0 into buffer 0
    STAGE(0, 0);

    for (int t = 0; t < 16; t++) {
        int cur = t & 1;
        drain_dma();       // own DMA complete (incl. prefetch issued last iter)
        __syncthreads();   // buf[cur] fully staged by all waves
        if (t < 15) STAGE(t + 1, cur ^ 1);

        // S^T - 16 = K @ Q^T - 16 : D[key][q], col=l16=q, row=quad*4+r=key
        // half a: keys 0..63 -> st0; half b: keys 64..127 -> st1
        floatx4 st0[4], st1[4];
#pragma unroll
        for (int ns = 0; ns < 4; ns++) { st0[ns] = m16; st1[ns] = m16; }
        __builtin_amdgcn_s_setprio(1);
#pragma unroll
        for (int ns = 0; ns < 4; ns++)
#pragma unroll
            for (int kk = 0; kk < 2; kk++) {
                bf16x8 kf = *(const bf16x8*)
                    &Ks[cur][ns * 16 + l16][(kk * 32 + quad * 8) ^ sw];
                st0[ns] = __builtin_amdgcn_mfma_f32_16x16x32_bf16(
                    kf, qf[kk], st0[ns], 0, 0, 0);
            }
#pragma unroll
        for (int ns = 0; ns < 4; ns++)
#pragma unroll
            for (int kk = 0; kk < 2; kk++) {
                bf16x8 kf = *(const bf16x8*)
                    &Ks[cur][(ns + 4) * 16 + l16][(kk * 32 + quad * 8) ^ sw];
                st1[ns] = __builtin_amdgcn_mfma_f32_16x16x32_bf16(
                    kf, qf[kk], st1[ns], 0, 0, 0);
            }
        __builtin_amdgcn_s_setprio(0);

        // SM(a): P^T = exp2(S^T) keys 0..63, repacked as PV B-operand frags
        bf16x8 pf0[2];
#pragma unroll
        for (int kk = 0; kk < 2; kk++)
#pragma unroll
            for (int tt = 0; tt < 8; tt++)
                pf0[kk][tt] = (bf16_t)__builtin_amdgcn_exp2f(
                    st0[2 * kk + (tt >> 2)][tt & 3]);

        // PV(a): O^T += V^T @ P (keys 0..63); l via ones-MFMA
        __builtin_amdgcn_s_setprio(1);
#pragma unroll
        for (int nd = 0; nd < 4; nd++)
#pragma unroll
            for (int kk = 0; kk < 2; kk++) {
                bf16x8 vf = *(const bf16x8*)
                    &Vs[cur][0][nd * 16 + l16][(kk * 32 + quad * 8) ^ sw];
                o_acc[nd] = __builtin_amdgcn_mfma_f32_16x16x32_bf16(
                    vf, pf0[kk], o_acc[nd], 0, 0, 0);
            }
#pragma unroll
        for (int kk = 0; kk < 2; kk++)
            l_acc = __builtin_amdgcn_mfma_f32_16x16x32_bf16(
                ones, pf0[kk], l_acc, 0, 0, 0);
        __builtin_amdgcn_s_setprio(0);

        // SM(b): keys 64..127 (overlaps PV(a) on the trans/VALU pipes)
        bf16x8 pf1[2];
#pragma unroll
        for (int kk = 0; kk < 2; kk++)
#pragma unroll
            for (int tt = 0; tt < 8; tt++)
                pf1[kk][tt] = (bf16_t)__builtin_amdgcn_exp2f(
                    st1[2 * kk + (tt >> 2)][tt & 3]);

        // PV(b): keys 64..127 (V half 1)
        __builtin_amdgcn_s_setprio(1);
#pragma unroll
        for (int nd = 0; nd < 4; nd++)
#pragma unroll
            for (int kk = 0; kk < 2; kk++) {
                bf16x8 vf = *(const bf16x8*)
                    &Vs[cur][1][nd * 16 + l16][(kk * 32 + quad * 8) ^ sw];
                o_acc[nd] = __builtin_amdgcn_mfma_f32_16x16x32_bf16(
                    vf, pf1[kk], o_acc[nd], 0, 0, 0);
            }
#pragma unroll
        for (int kk = 0; kk < 2; kk++)
            l_acc = __builtin_amdgcn_mfma_f32_16x16x32_bf16(
                ones, pf1[kk], l_acc, 0, 0, 0);
        __builtin_amdgcn_s_setprio(0);
    }

    // l_acc: every reg r of every quad holds the complete l for q = l16.
    float inv = 1.f / l_acc[0];
    int q = qw + l16;
    bf16_t* ob = O + ((size_t)b * SEQ + q) * EMBED + h * HDIM;
#pragma unroll
    for (int nd = 0; nd < 4; nd++)
#pragma unroll
        for (int r = 0; r < 4; r++)
            ob[nd * 16 + quad * 4 + r] = (bf16_t)(o_acc[nd][r] * inv);
}

// ---------------------------------------------------------------------------
// Workspace layout (bytes):
//   [0,  8MB): W^T bf16 (4 x 1M)
//   [8, 16MB): x bf16 [4096,1024]
//   [16,40MB): Q,K bf16 [b,h,s,d] (Q scaled by QSCALE); V slot unused
//   [40,48MB): Vt bf16 [b,h,d,s'] (key-permuted per 64-block, PV-operand map)
//   [48,56MB): attention out bf16 [b,s,h*d]
// ---------------------------------------------------------------------------
extern "C" void kernel_launch(void* const* d_in, const int* in_sizes, int n_in,
                              void* d_out, int out_size, void* d_ws, size_t ws_size,
                              hipStream_t stream)
{
    const float* x  = (const float*)d_in[0];
    const float* wq = (const float*)d_in[1];
    const float* bq = (const float*)d_in[2];
    const float* wk = (const float*)d_in[3];
    const float* bk = (const float*)d_in[4];
    const float* wv = (const float*)d_in[5];
    const float* bv = (const float*)d_in[6];
    const float* wo = (const float*)d_in[7];
    const float* bo = (const float*)d_in[8];

    char*   ws    = (char*)d_ws;
    bf16_t* Wt    = (bf16_t*)ws;                           // 4 x 1048576 bf16
    bf16_t* Xb    = (bf16_t*)(ws + 8ull  * 1024 * 1024);   // 4194304 bf16
    bf16_t* QKV   = (bf16_t*)(ws + 16ull * 1024 * 1024);   // 3 x 4194304 bf16
    bf16_t* Vt    = (bf16_t*)(ws + 40ull * 1024 * 1024);   // 4194304 bf16
    bf16_t* attnO = (bf16_t*)(ws + 48ull * 1024 * 1024);   // 4194304 bf16
    float*  outp  = (float*)d_out;

    // weights transpose + x convert, one launch
    transpose4<<<dim3(32, 32, 8), dim3(32, 8), 0, stream>>>(
        wq, wk, wv, wo, x, Wt, Xb);

    // fused QKV projection: Q/K -> [b,h,s,d]; V -> Vt [b,h,d,s'] directly
    // 1-D grid 768: id%8 = m-group (A rows L2-local per XCD)  [R5 decode]
    gemm_t<128, 1><<<dim3(768), 256, 0, stream>>>(
        Xb, Wt, bq, bk, bv, QKV, Vt, MTOT, 3072, EMBED);

    attn_mfma<<<dim3(512), 512, 0, stream>>>(
        QKV, QKV + 4194304u, Vt, attnO);

    // output projection: [4096,1024] @ [1024,1024] -> d_out (fp32)
    // BM=64 grid 512 (R5 config: 2 blocks/CU beats BM=128 @ 1 block/CU, R7)
    gemm_t<64, 0><<<dim3(512), 256, 0, stream>>>(
        attnO, Wt + 3u * 1048576u, bo, bo, bo, outp, nullptr, MTOT, EMBED, EMBED);
}

// Round 9
// 174.827 us; speedup vs baseline: 1.0165x; 1.0105x over previous
//
#include <hip/hip_runtime.h>
#include <cstdint>

typedef __bf16 bf16_t;
typedef __bf16 bf16x4 __attribute__((ext_vector_type(4)));
typedef __bf16 bf16x8 __attribute__((ext_vector_type(8)));
typedef float floatx4 __attribute__((ext_vector_type(4)));

#define EMBED 1024
#define NHEAD 16
#define HDIM  64
#define SEQ   2048
#define BATCH 2
#define MTOT  (BATCH*SEQ)   /* 4096 */
// Q is pre-scaled by 1/sqrt(64) * log2(e) so softmax can use exp2
#define QSCALE 0.18033688011112042f

// async global->LDS, 16B per lane; LDS dest = wave-uniform base + lane*16
__device__ __forceinline__ void gload16(const bf16_t* g, bf16_t* l) {
    __builtin_amdgcn_global_load_lds(
        (const __attribute__((address_space(1))) void*)g,
        (__attribute__((address_space(3))) void*)l, 16, 0, 0);
}

// Explicit drain of the wave's own outstanding LDS-DMA (global_load_lds is
// tracked in vmcnt). __syncthreads() alone is NOT guaranteed to emit
// vmcnt(0) before s_barrier for LDS-DMA ops on every compiler build; the
// 1-deep double-buffer protocol is racy without it (warm-replay failures).
__device__ __forceinline__ void drain_dma() {
    asm volatile("s_waitcnt vmcnt(0)" ::: "memory");
}

// ---------------------------------------------------------------------------
// z<4 : transpose fp32 weight z into bf16 [n][k] (W^T)
// z>=4: straight convert slab z-4 of x fp32 -> bf16
// (exact R5 champion version)
// ---------------------------------------------------------------------------
__global__ __launch_bounds__(256) void transpose4(
    const float* __restrict__ w0, const float* __restrict__ w1,
    const float* __restrict__ w2, const float* __restrict__ w3,
    const float* __restrict__ xin,
    bf16_t* __restrict__ out, bf16_t* __restrict__ xout)
{
    int z = blockIdx.z;
    int tx = threadIdx.x, ty = threadIdx.y;   // block (32,8)
    if (z >= 4) {
        const float* src = xin  + (size_t)(z - 4) * 1048576u;
        bf16_t*      dst = xout + (size_t)(z - 4) * 1048576u;
        int col = blockIdx.x * 32 + tx, rowb = blockIdx.y * 32;
#pragma unroll
        for (int j = 0; j < 4; j++) {
            int rr = rowb + ty + 8 * j;
            dst[(size_t)rr * 1024 + col] = (bf16_t)src[(size_t)rr * 1024 + col];
        }
        return;
    }
    __shared__ float t[32][33];
    const float* src = (z == 0) ? w0 : (z == 1) ? w1 : (z == 2) ? w2 : w3;
    bf16_t* dst = out + (size_t)z * 1048576u;
    int bx = blockIdx.x * 32, by = blockIdx.y * 32;
#pragma unroll
    for (int j = 0; j < 4; j++)
        t[ty + 8 * j][tx] = src[(size_t)(by + ty + 8 * j) * EMBED + bx + tx];
    __syncthreads();
#pragma unroll
    for (int j = 0; j < 4; j++)
        dst[(size_t)(bx + ty + 8 * j) * EMBED + by + tx] = (bf16_t)t[tx][ty + 8 * j];
}

// ---------------------------------------------------------------------------
// MFMA GEMM v2 (R5): global_load_lds DMA staging + LDS DOUBLE-BUFFER + one
// barrier per K-iter (explicit vmcnt(0) drain). XOR chunk swizzle via the
// DMA source address. 1-D grid, XCD swizzle: id%8 = m-group.
// MODE 0: fp32 out row-major.
// MODE 1: fused QKV. Q/K tiles (n0<2048) scatter to bf16 [b,h,s,d] (Q scaled
//         by QSCALE). V tiles (n0>=2048) transpose through LDS and write
//         Vt [b,h,d,s'] with the PV-operand key permutation folded in.
// ---------------------------------------------------------------------------
template<int BM, int MODE>
__global__ __launch_bounds__(256) void gemm_t(
    const bf16_t* __restrict__ A,  const bf16_t* __restrict__ Bt,
    const float* __restrict__ bias0, const float* __restrict__ bias1,
    const float* __restrict__ bias2,
    void* __restrict__ outraw, bf16_t* __restrict__ vtout,
    int M, int N, int K)
{
    constexpr int MS = BM / 32;          // m-subtiles per wave
    constexpr int BUFSZ = (BM + 128) * 64;
    __shared__ __align__(16) bf16_t smem[2 * BUFSZ];

    int tid  = threadIdx.x;
    // XCD-aware decode: id%8 = m-group -> same-XCD blocks share A rows
    int id   = blockIdx.x;
    int c8   = id & 7, rr_ = id >> 3;
    int nblk = N >> 7;
    int n0   = (rr_ % nblk) * 128;
    int m0   = ((rr_ / nblk) * 8 + c8) * BM;
    int wv   = tid >> 6, lane = tid & 63;
    int wr   = wv >> 1,  wc   = wv & 1;
    int quad = lane >> 4, l16 = lane & 15;
    int lr   = lane >> 3, lq = lane & 7;
    int sw   = (l16 & 7) * 8;                    // reader swizzle (elems)
    int lcs  = ((lq ^ lr) * 8);                  // DMA source chunk (elems)

    floatx4 acc[MS][4];
    floatx4 z4 = {0.f, 0.f, 0.f, 0.f};
#pragma unroll
    for (int mi = 0; mi < MS; mi++)
#pragma unroll
        for (int ni = 0; ni < 4; ni++) acc[mi][ni] = z4;

    auto STAGE = [&](int k0, int buf) {
        bf16_t* as = smem + buf * BUFSZ;
        bf16_t* bs = as + BM * 64;
#pragma unroll
        for (int i = 0; i < BM / 32; i++) {
            int r = wv * (BM / 4) + i * 8;
            gload16(&A[(size_t)(m0 + r + lr) * K + k0 + lcs], as + r * 64);
        }
#pragma unroll
        for (int i = 0; i < 4; i++) {
            int r = wv * 32 + i * 8;
            gload16(&Bt[(size_t)(n0 + r + lr) * K + k0 + lcs], bs + r * 64);
        }
    };

    STAGE(0, 0);
    int T = K >> 6;
    for (int t = 0; t < T; t++) {
        int cur = t & 1;
        drain_dma();                     // own DMA (incl. prefetch) complete
        __syncthreads();                 // buf[cur] DMA complete (1-tile cover)
        if (t + 1 < T) STAGE((t + 1) << 6, cur ^ 1);
        bf16_t (*As)[64] = (bf16_t(*)[64])(smem + cur * BUFSZ);
        bf16_t (*Bs)[64] = (bf16_t(*)[64])(smem + cur * BUFSZ + BM * 64);
#pragma unroll
        for (int kk = 0; kk < 2; kk++) {
            bf16x8 af[MS], bfr[4];
            int co = kk * 32 + quad * 8;
#pragma unroll
            for (int i = 0; i < MS; i++)
                af[i]  = *(const bf16x8*)&As[wr * (BM / 2) + i * 16 + l16][co ^ sw];
#pragma unroll
            for (int i = 0; i < 4; i++)
                bfr[i] = *(const bf16x8*)&Bs[wc * 64 + i * 16 + l16][co ^ sw];
#pragma unroll
            for (int mi = 0; mi < MS; mi++)
#pragma unroll
                for (int ni = 0; ni < 4; ni++)
                    acc[mi][ni] = __builtin_amdgcn_mfma_f32_16x16x32_bf16(
                        af[mi], bfr[ni], acc[mi][ni], 0, 0, 0);
        }
    }

    if constexpr (MODE == 1) {
        if (n0 >= 2048) {
            // ------- V tile: LDS transpose + permuted coalesced Vt write ----
            bf16_t (*Ts)[72] = (bf16_t(*)[72])smem;   // 128 hd x 64 s' (+pad)
            int bb = m0 >> 11, s0 = m0 & 2047;
            int hd0 = n0 & 1023;
#pragma unroll
            for (int mh = 0; mh < 2; mh++) {
                __syncthreads();
                if (wr == mh) {
#pragma unroll
                    for (int mi = 0; mi < MS; mi++)
#pragma unroll
                        for (int ni = 0; ni < 4; ni++)
#pragma unroll
                            for (int r = 0; r < 4; r++) {
                                int ml = mi * 16 + quad * 4 + r;     // 0..63
                                int nl = wc * 64 + ni * 16 + l16;    // 0..127
                                float v = acc[mi][ni][r] + bias2[hd0 + nl];
                                int sp = ((ml >> 5) << 5) | (((ml >> 2) & 3) << 3)
                                       | (((ml >> 4) & 1) << 2) | (ml & 3);
                                Ts[nl][sp] = (bf16_t)v;
                            }
                }
                __syncthreads();
#pragma unroll
                for (int i = 0; i < 4; i++) {
                    int c = tid + i * 256;          // 1024 chunk-writes
                    int row = c >> 3, ch = (c & 7) * 8;
                    int hh = row >> 6, dd = row & 63;
                    size_t off = (((size_t)bb * NHEAD + (hd0 >> 6) + hh) * HDIM + dd) * SEQ
                               + (size_t)(s0 + mh * 64 + ch);
                    *(bf16x8*)&vtout[off] = *(const bf16x8*)&Ts[row][ch];
                }
            }
            return;
        }
    }

    // epilogue: C/D layout col = lane&15 (n), row = quad*4 + reg (m)
#pragma unroll
    for (int mi = 0; mi < MS; mi++) {
#pragma unroll
        for (int ni = 0; ni < 4; ni++) {
            int n = n0 + wc * 64 + ni * 16 + l16;
#pragma unroll
            for (int r = 0; r < 4; r++) {
                int m = m0 + wr * (BM / 2) + mi * 16 + quad * 4 + r;
                float v = acc[mi][ni][r];
                if (MODE == 0) {
                    ((float*)outraw)[(size_t)m * N + n] = v + bias0[n];
                } else {
                    int which = n >> 10, cc = n & 1023;   // 0=Q, 1=K here
                    v += (which == 0) ? bias0[cc] : bias1[cc];
                    if (which == 0) v *= QSCALE;
                    int h = cc >> 6, d = cc & 63;
                    int b = m >> 11, s = m & 2047;
                    ((bf16_t*)outraw)[(size_t)which * 4194304u +
                        (((size_t)b * NHEAD + h) * SEQ + s) * HDIM + d] = (bf16_t)v;
                }
            }
        }
    }
}

// ---------------------------------------------------------------------------
// MFMA flash attention v7 (R5 champion):
// S^T-trick, KVBLK=128 (16 iters), V as two half-tiles Vs[buf][half][64][64]
// (verified conflict-free), l via ones-MFMA, half-split QK/SM/PV pipeline,
// DMA double-buffer + explicit vmcnt drain.
// ---------------------------------------------------------------------------
__global__ __launch_bounds__(512, 4) void attn_mfma(
    const bf16_t* __restrict__ Q, const bf16_t* __restrict__ K,
    const bf16_t* __restrict__ Vt, bf16_t* __restrict__ O)
{
    __shared__ __align__(16) bf16_t Ks[2][128][64];     // [buf][key][dim]
    __shared__ __align__(16) bf16_t Vs[2][2][64][64];   // [buf][half][dim][key]

    int tid  = threadIdx.x;
    int wv   = tid >> 6, lane = tid & 63;            // wv 0..7
    int quad = lane >> 4, l16 = lane & 15;
    int sw   = (l16 & 7) * 8;
    int lr8  = lane >> 3, lq8  = lane & 7;           // staging decomp
    int flat = blockIdx.x;
    int hb   = flat & 31;               // head-batch group; XCD = flat%8 = hb%8
    int qt   = flat >> 5;               // q-tile 0..15 (128 rows each)
    int h = hb & 15, b = hb >> 4;
    int bh = b * NHEAD + h;
    int qw = qt * 128 + wv * 16;        // wave's 16 query rows

    const bf16_t* Qb = Q  + (size_t)bh * SEQ * HDIM;
    const bf16_t* Kb = K  + (size_t)bh * SEQ * HDIM;
    const bf16_t* Vb = Vt + (size_t)bh * SEQ * HDIM;   // row d, col key'

    // staging: waves 0-3 -> K rows [wv*32, +32) (4 gload16).
    // waves 4-7 -> V half (w>>1), dims (w&1)*32 + [0..31] (4 gload16),
    // v4-style per-row chunk swizzle (lq8 ^ lr8).
    int vwave = wv >> 2;
    int w3    = wv & 3;
    const bf16_t* kgp = Kb + (size_t)(wv * 32 + lr8) * HDIM + (lq8 ^ lr8) * 8;
    int vhalf = w3 >> 1, vd0 = (w3 & 1) * 32;
    const bf16_t* vgp = Vb + (size_t)(vd0 + lr8) * SEQ + vhalf * 64
                           + (size_t)((lq8 ^ lr8) * 8);

    auto STAGE = [&](int t, int buf) {
        if (!vwave) {
            const bf16_t* g = kgp + (size_t)t * (128u * HDIM);
            bf16_t* l = &Ks[buf][wv * 32][0];
            gload16(g,             l);
            gload16(g +  8 * HDIM, l +  8 * 64);
            gload16(g + 16 * HDIM, l + 16 * 64);
            gload16(g + 24 * HDIM, l + 24 * 64);
        } else {
            const bf16_t* g = vgp + (size_t)t * 128u;
            bf16_t* l = &Vs[buf][vhalf][vd0][0];
            gload16(g,            l);
            gload16(g +  8 * SEQ, l +  8 * 64);
            gload16(g + 16 * SEQ, l + 16 * 64);
            gload16(g + 24 * SEQ, l + 24 * 64);
        }
    };

    // Q fragments (B-operand: n=q=l16, k=dims), registers for whole kernel
    bf16x8 qf[2];
#pragma unroll
    for (int kk = 0; kk < 2; kk++)
        qf[kk] = *(const bf16x8*)
            &Qb[(size_t)(qw + l16) * HDIM + kk * 32 + quad * 8];

    bf16x8 ones;
#pragma unroll
    for (int i = 0; i < 8; i++) ones[i] = (bf16_t)1.0f;

    floatx4 o_acc[4];
    floatx4 z4  = {0.f, 0.f, 0.f, 0.f};
    floatx4 m16 = {-16.f, -16.f, -16.f, -16.f};
#pragma unroll
    for (int nd = 0; nd < 4; nd++) o_acc[nd] = z4;
    floatx4 l_acc = z4;

    // prologue: stage tile 0 into buffer 0
    STAGE(0, 0);

    for (int t = 0; t < 16; t++) {
        int cur = t & 1;
        drain_dma();       // own DMA complete (incl. prefetch issued last iter)
        __syncthreads();   // buf[cur] fully staged by all waves
        if (t < 15) STAGE(t + 1, cur ^ 1);

        // S^T - 16 = K @ Q^T - 16 : D[key][q], col=l16=q, row=quad*4+r=key
        // half a: keys 0..63 -> st0; half b: keys 64..127 -> st1
        floatx4 st0[4], st1[4];
#pragma unroll
        for (int ns = 0; ns < 4; ns++) { st0[ns] = m16; st1[ns] = m16; }
        __builtin_amdgcn_s_setprio(1);
#pragma unroll
        for (int ns = 0; ns < 4; ns++)
#pragma unroll
            for (int kk = 0; kk < 2; kk++) {
                bf16x8 kf = *(const bf16x8*)
                    &Ks[cur][ns * 16 + l16][(kk * 32 + quad * 8) ^ sw];
                st0[ns] = __builtin_amdgcn_mfma_f32_16x16x32_bf16(
                    kf, qf[kk], st0[ns], 0, 0, 0);
            }
#pragma unroll
        for (int ns = 0; ns < 4; ns++)
#pragma unroll
            for (int kk = 0; kk < 2; kk++) {
                bf16x8 kf = *(const bf16x8*)
                    &Ks[cur][(ns + 4) * 16 + l16][(kk * 32 + quad * 8) ^ sw];
                st1[ns] = __builtin_amdgcn_mfma_f32_16x16x32_bf16(
                    kf, qf[kk], st1[ns], 0, 0, 0);
            }
        __builtin_amdgcn_s_setprio(0);

        // SM(a): P^T = exp2(S^T) keys 0..63, repacked as PV B-operand frags
        bf16x8 pf0[2];
#pragma unroll
        for (int kk = 0; kk < 2; kk++)
#pragma unroll
            for (int tt = 0; tt < 8; tt++)
                pf0[kk][tt] = (bf16_t)__builtin_amdgcn_exp2f(
                    st0[2 * kk + (tt >> 2)][tt & 3]);

        // PV(a): O^T += V^T @ P (keys 0..63); l via ones-MFMA
        __builtin_amdgcn_s_setprio(1);
#pragma unroll
        for (int nd = 0; nd < 4; nd++)
#pragma unroll
            for (int kk = 0; kk < 2; kk++) {
                bf16x8 vf = *(const bf16x8*)
                    &Vs[cur][0][nd * 16 + l16][(kk * 32 + quad * 8) ^ sw];
                o_acc[nd] = __builtin_amdgcn_mfma_f32_16x16x32_bf16(
                    vf, pf0[kk], o_acc[nd], 0, 0, 0);
            }
#pragma unroll
        for (int kk = 0; kk < 2; kk++)
            l_acc = __builtin_amdgcn_mfma_f32_16x16x32_bf16(
                ones, pf0[kk], l_acc, 0, 0, 0);
        __builtin_amdgcn_s_setprio(0);

        // SM(b): keys 64..127 (overlaps PV(a) on the trans/VALU pipes)
        bf16x8 pf1[2];
#pragma unroll
        for (int kk = 0; kk < 2; kk++)
#pragma unroll
            for (int tt = 0; tt < 8; tt++)
                pf1[kk][tt] = (bf16_t)__builtin_amdgcn_exp2f(
                    st1[2 * kk + (tt >> 2)][tt & 3]);

        // PV(b): keys 64..127 (V half 1)
        __builtin_amdgcn_s_setprio(1);
#pragma unroll
        for (int nd = 0; nd < 4; nd++)
#pragma unroll
            for (int kk = 0; kk < 2; kk++) {
                bf16x8 vf = *(const bf16x8*)
                    &Vs[cur][1][nd * 16 + l16][(kk * 32 + quad * 8) ^ sw];
                o_acc[nd] = __builtin_amdgcn_mfma_f32_16x16x32_bf16(
                    vf, pf1[kk], o_acc[nd], 0, 0, 0);
            }
#pragma unroll
        for (int kk = 0; kk < 2; kk++)
            l_acc = __builtin_amdgcn_mfma_f32_16x16x32_bf16(
                ones, pf1[kk], l_acc, 0, 0, 0);
        __builtin_amdgcn_s_setprio(0);
    }

    // l_acc: every reg r of every quad holds the complete l for q = l16.
    float inv = 1.f / l_acc[0];
    int q = qw + l16;
    bf16_t* ob = O + ((size_t)b * SEQ + q) * EMBED + h * HDIM;
#pragma unroll
    for (int nd = 0; nd < 4; nd++)
#pragma unroll
        for (int r = 0; r < 4; r++)
            ob[nd * 16 + quad * 4 + r] = (bf16_t)(o_acc[nd][r] * inv);
}

// ---------------------------------------------------------------------------
// Workspace layout (bytes):
//   [0,  8MB): W^T bf16 (4 x 1M)
//   [8, 16MB): x bf16 [4096,1024]
//   [16,40MB): Q,K bf16 [b,h,s,d] (Q scaled by QSCALE); V slot unused
//   [40,48MB): Vt bf16 [b,h,d,s'] (key-permuted per 64-block, PV-operand map)
//   [48,56MB): attention out bf16 [b,s,h*d]
// ---------------------------------------------------------------------------
extern "C" void kernel_launch(void* const* d_in, const int* in_sizes, int n_in,
                              void* d_out, int out_size, void* d_ws, size_t ws_size,
                              hipStream_t stream)
{
    const float* x  = (const float*)d_in[0];
    const float* wq = (const float*)d_in[1];
    const float* bq = (const float*)d_in[2];
    const float* wk = (const float*)d_in[3];
    const float* bk = (const float*)d_in[4];
    const float* wv = (const float*)d_in[5];
    const float* bv = (const float*)d_in[6];
    const float* wo = (const float*)d_in[7];
    const float* bo = (const float*)d_in[8];

    char*   ws    = (char*)d_ws;
    bf16_t* Wt    = (bf16_t*)ws;                           // 4 x 1048576 bf16
    bf16_t* Xb    = (bf16_t*)(ws + 8ull  * 1024 * 1024);   // 4194304 bf16
    bf16_t* QKV   = (bf16_t*)(ws + 16ull * 1024 * 1024);   // 3 x 4194304 bf16
    bf16_t* Vt    = (bf16_t*)(ws + 40ull * 1024 * 1024);   // 4194304 bf16
    bf16_t* attnO = (bf16_t*)(ws + 48ull * 1024 * 1024);   // 4194304 bf16
    float*  outp  = (float*)d_out;

    // weights transpose + x convert, one launch
    transpose4<<<dim3(32, 32, 8), dim3(32, 8), 0, stream>>>(
        wq, wk, wv, wo, x, Wt, Xb);

    // fused QKV projection: Q/K -> [b,h,s,d]; V -> Vt [b,h,d,s'] directly
    // 1-D grid 768: id%8 = m-group (A rows L2-local per XCD)
    gemm_t<128, 1><<<dim3(768), 256, 0, stream>>>(
        Xb, Wt, bq, bk, bv, QKV, Vt, MTOT, 3072, EMBED);

    attn_mfma<<<dim3(512), 512, 0, stream>>>(
        QKV, QKV + 4194304u, Vt, attnO);

    // output projection: [4096,1024] @ [1024,1024] -> d_out (fp32)
    // BM=64 grid 512 (2 blocks/CU beats BM=128 @ 1 block/CU, per R7)
    gemm_t<64, 0><<<dim3(512), 256, 0, stream>>>(
        attnO, Wt + 3u * 1048576u, bo, bo, bo, outp, nullptr, MTOT, EMBED, EMBED);
}

// Round 10
// 174.631 us; speedup vs baseline: 1.0177x; 1.0011x over previous
//
#include <hip/hip_runtime.h>
#include <cstdint>

typedef __bf16 bf16_t;
typedef __bf16 bf16x4 __attribute__((ext_vector_type(4)));
typedef __bf16 bf16x8 __attribute__((ext_vector_type(8)));
typedef float floatx4 __attribute__((ext_vector_type(4)));

#define EMBED 1024
#define NHEAD 16
#define HDIM  64
#define SEQ   2048
#define BATCH 2
#define MTOT  (BATCH*SEQ)   /* 4096 */
// Q is pre-scaled by 1/sqrt(64) * log2(e) so softmax can use exp2
#define QSCALE 0.18033688011112042f

// async global->LDS, 16B per lane; LDS dest = wave-uniform base + lane*16
__device__ __forceinline__ void gload16(const bf16_t* g, bf16_t* l) {
    __builtin_amdgcn_global_load_lds(
        (const __attribute__((address_space(1))) void*)g,
        (__attribute__((address_space(3))) void*)l, 16, 0, 0);
}

// Explicit drain of the wave's own outstanding LDS-DMA (global_load_lds is
// tracked in vmcnt). __syncthreads() alone is NOT guaranteed to emit
// vmcnt(0) before s_barrier for LDS-DMA ops on every compiler build; the
// 1-deep double-buffer protocol is racy without it (warm-replay failures).
__device__ __forceinline__ void drain_dma() {
    asm volatile("s_waitcnt vmcnt(0)" ::: "memory");
}

// ---------------------------------------------------------------------------
// z<4 : transpose fp32 weight z into bf16 [n][k] (W^T)
// z>=4: straight convert slab z-4 of x fp32 -> bf16
// (exact R5 champion version)
// ---------------------------------------------------------------------------
__global__ __launch_bounds__(256) void transpose4(
    const float* __restrict__ w0, const float* __restrict__ w1,
    const float* __restrict__ w2, const float* __restrict__ w3,
    const float* __restrict__ xin,
    bf16_t* __restrict__ out, bf16_t* __restrict__ xout)
{
    int z = blockIdx.z;
    int tx = threadIdx.x, ty = threadIdx.y;   // block (32,8)
    if (z >= 4) {
        const float* src = xin  + (size_t)(z - 4) * 1048576u;
        bf16_t*      dst = xout + (size_t)(z - 4) * 1048576u;
        int col = blockIdx.x * 32 + tx, rowb = blockIdx.y * 32;
#pragma unroll
        for (int j = 0; j < 4; j++) {
            int rr = rowb + ty + 8 * j;
            dst[(size_t)rr * 1024 + col] = (bf16_t)src[(size_t)rr * 1024 + col];
        }
        return;
    }
    __shared__ float t[32][33];
    const float* src = (z == 0) ? w0 : (z == 1) ? w1 : (z == 2) ? w2 : w3;
    bf16_t* dst = out + (size_t)z * 1048576u;
    int bx = blockIdx.x * 32, by = blockIdx.y * 32;
#pragma unroll
    for (int j = 0; j < 4; j++)
        t[ty + 8 * j][tx] = src[(size_t)(by + ty + 8 * j) * EMBED + bx + tx];
    __syncthreads();
#pragma unroll
    for (int j = 0; j < 4; j++)
        dst[(size_t)(bx + ty + 8 * j) * EMBED + by + tx] = (bf16_t)t[tx][ty + 8 * j];
}

// ---------------------------------------------------------------------------
// MFMA GEMM v2 (R5): global_load_lds DMA staging + LDS DOUBLE-BUFFER + one
// barrier per K-iter (explicit vmcnt(0) drain). XOR chunk swizzle via the
// DMA source address.
// XCD decode (R10): id%8 = XCD slot. MODE 1 uses m-major-within-XCD so 4
// consecutive same-XCD blocks reuse one 256KB B-panel from L2 before moving
// to the next n-panel (was n-major: 24 panels = 6MB streamed per XCD).
// Per-XCD A-slice = 4 m-groups x 128 rows = 1MB, L2-resident. Bijective.
// MODE 0: fp32 out row-major.
// MODE 1: fused QKV. Q/K tiles (n0<2048) scatter to bf16 [b,h,s,d] (Q scaled
//         by QSCALE). V tiles (n0>=2048) transpose through LDS and write
//         Vt [b,h,d,s'] with the PV-operand key permutation folded in.
// ---------------------------------------------------------------------------
template<int BM, int MODE>
__global__ __launch_bounds__(256) void gemm_t(
    const bf16_t* __restrict__ A,  const bf16_t* __restrict__ Bt,
    const float* __restrict__ bias0, const float* __restrict__ bias1,
    const float* __restrict__ bias2,
    void* __restrict__ outraw, bf16_t* __restrict__ vtout,
    int M, int N, int K)
{
    constexpr int MS = BM / 32;          // m-subtiles per wave
    constexpr int BUFSZ = (BM + 128) * 64;
    __shared__ __align__(16) bf16_t smem[2 * BUFSZ];

    int tid  = threadIdx.x;
    int id   = blockIdx.x;
    int c8   = id & 7, rr_ = id >> 3;
    int n0, m0;
    if constexpr (MODE == 1) {
        // m-major within XCD: rr_ 0..95 -> n-panel rr_>>2 (0..23),
        // m-sub rr_&3; m-group = (rr_&3)*8 + c8 (0..31). Bijective.
        n0 = (rr_ >> 2) * 128;
        m0 = (((rr_ & 3) * 8 + c8)) * BM;
    } else {
        int nblk = N >> 7;
        n0 = (rr_ % nblk) * 128;
        m0 = ((rr_ / nblk) * 8 + c8) * BM;
    }
    int wv   = tid >> 6, lane = tid & 63;
    int wr   = wv >> 1,  wc   = wv & 1;
    int quad = lane >> 4, l16 = lane & 15;
    int lr   = lane >> 3, lq = lane & 7;
    int sw   = (l16 & 7) * 8;                    // reader swizzle (elems)
    int lcs  = ((lq ^ lr) * 8);                  // DMA source chunk (elems)

    floatx4 acc[MS][4];
    floatx4 z4 = {0.f, 0.f, 0.f, 0.f};
#pragma unroll
    for (int mi = 0; mi < MS; mi++)
#pragma unroll
        for (int ni = 0; ni < 4; ni++) acc[mi][ni] = z4;

    auto STAGE = [&](int k0, int buf) {
        bf16_t* as = smem + buf * BUFSZ;
        bf16_t* bs = as + BM * 64;
#pragma unroll
        for (int i = 0; i < BM / 32; i++) {
            int r = wv * (BM / 4) + i * 8;
            gload16(&A[(size_t)(m0 + r + lr) * K + k0 + lcs], as + r * 64);
        }
#pragma unroll
        for (int i = 0; i < 4; i++) {
            int r = wv * 32 + i * 8;
            gload16(&Bt[(size_t)(n0 + r + lr) * K + k0 + lcs], bs + r * 64);
        }
    };

    STAGE(0, 0);
    int T = K >> 6;
    for (int t = 0; t < T; t++) {
        int cur = t & 1;
        drain_dma();                     // own DMA (incl. prefetch) complete
        __syncthreads();                 // buf[cur] DMA complete (1-tile cover)
        if (t + 1 < T) STAGE((t + 1) << 6, cur ^ 1);
        bf16_t (*As)[64] = (bf16_t(*)[64])(smem + cur * BUFSZ);
        bf16_t (*Bs)[64] = (bf16_t(*)[64])(smem + cur * BUFSZ + BM * 64);
#pragma unroll
        for (int kk = 0; kk < 2; kk++) {
            bf16x8 af[MS], bfr[4];
            int co = kk * 32 + quad * 8;
#pragma unroll
            for (int i = 0; i < MS; i++)
                af[i]  = *(const bf16x8*)&As[wr * (BM / 2) + i * 16 + l16][co ^ sw];
#pragma unroll
            for (int i = 0; i < 4; i++)
                bfr[i] = *(const bf16x8*)&Bs[wc * 64 + i * 16 + l16][co ^ sw];
#pragma unroll
            for (int mi = 0; mi < MS; mi++)
#pragma unroll
                for (int ni = 0; ni < 4; ni++)
                    acc[mi][ni] = __builtin_amdgcn_mfma_f32_16x16x32_bf16(
                        af[mi], bfr[ni], acc[mi][ni], 0, 0, 0);
        }
    }

    if constexpr (MODE == 1) {
        if (n0 >= 2048) {
            // ------- V tile: LDS transpose + permuted coalesced Vt write ----
            bf16_t (*Ts)[72] = (bf16_t(*)[72])smem;   // 128 hd x 64 s' (+pad)
            int bb = m0 >> 11, s0 = m0 & 2047;
            int hd0 = n0 & 1023;
#pragma unroll
            for (int mh = 0; mh < 2; mh++) {
                __syncthreads();
                if (wr == mh) {
#pragma unroll
                    for (int mi = 0; mi < MS; mi++)
#pragma unroll
                        for (int ni = 0; ni < 4; ni++)
#pragma unroll
                            for (int r = 0; r < 4; r++) {
                                int ml = mi * 16 + quad * 4 + r;     // 0..63
                                int nl = wc * 64 + ni * 16 + l16;    // 0..127
                                float v = acc[mi][ni][r] + bias2[hd0 + nl];
                                int sp = ((ml >> 5) << 5) | (((ml >> 2) & 3) << 3)
                                       | (((ml >> 4) & 1) << 2) | (ml & 3);
                                Ts[nl][sp] = (bf16_t)v;
                            }
                }
                __syncthreads();
#pragma unroll
                for (int i = 0; i < 4; i++) {
                    int c = tid + i * 256;          // 1024 chunk-writes
                    int row = c >> 3, ch = (c & 7) * 8;
                    int hh = row >> 6, dd = row & 63;
                    size_t off = (((size_t)bb * NHEAD + (hd0 >> 6) + hh) * HDIM + dd) * SEQ
                               + (size_t)(s0 + mh * 64 + ch);
                    *(bf16x8*)&vtout[off] = *(const bf16x8*)&Ts[row][ch];
                }
            }
            return;
        }
    }

    // epilogue: C/D layout col = lane&15 (n), row = quad*4 + reg (m)
#pragma unroll
    for (int mi = 0; mi < MS; mi++) {
#pragma unroll
        for (int ni = 0; ni < 4; ni++) {
            int n = n0 + wc * 64 + ni * 16 + l16;
#pragma unroll
            for (int r = 0; r < 4; r++) {
                int m = m0 + wr * (BM / 2) + mi * 16 + quad * 4 + r;
                float v = acc[mi][ni][r];
                if (MODE == 0) {
                    ((float*)outraw)[(size_t)m * N + n] = v + bias0[n];
                } else {
                    int which = n >> 10, cc = n & 1023;   // 0=Q, 1=K here
                    v += (which == 0) ? bias0[cc] : bias1[cc];
                    if (which == 0) v *= QSCALE;
                    int h = cc >> 6, d = cc & 63;
                    int b = m >> 11, s = m & 2047;
                    ((bf16_t*)outraw)[(size_t)which * 4194304u +
                        (((size_t)b * NHEAD + h) * SEQ + s) * HDIM + d] = (bf16_t)v;
                }
            }
        }
    }
}

// ---------------------------------------------------------------------------
// MFMA flash attention v7 (R5 champion, control):
// S^T-trick, KVBLK=128 (16 iters), V as two half-tiles Vs[buf][half][64][64]
// (verified conflict-free), l via ones-MFMA, half-split QK/SM/PV pipeline,
// DMA double-buffer + explicit vmcnt drain.
// ---------------------------------------------------------------------------
__global__ __launch_bounds__(512, 4) void attn_mfma(
    const bf16_t* __restrict__ Q, const bf16_t* __restrict__ K,
    const bf16_t* __restrict__ Vt, bf16_t* __restrict__ O)
{
    __shared__ __align__(16) bf16_t Ks[2][128][64];     // [buf][key][dim]
    __shared__ __align__(16) bf16_t Vs[2][2][64][64];   // [buf][half][dim][key]

    int tid  = threadIdx.x;
    int wv   = tid >> 6, lane = tid & 63;            // wv 0..7
    int quad = lane >> 4, l16 = lane & 15;
    int sw   = (l16 & 7) * 8;
    int lr8  = lane >> 3, lq8  = lane & 7;           // staging decomp
    int flat = blockIdx.x;
    int hb   = flat & 31;               // head-batch group; XCD = flat%8 = hb%8
    int qt   = flat >> 5;               // q-tile 0..15 (128 rows each)
    int h = hb & 15, b = hb >> 4;
    int bh = b * NHEAD + h;
    int qw = qt * 128 + wv * 16;        // wave's 16 query rows

    const bf16_t* Qb = Q  + (size_t)bh * SEQ * HDIM;
    const bf16_t* Kb = K  + (size_t)bh * SEQ * HDIM;
    const bf16_t* Vb = Vt + (size_t)bh * SEQ * HDIM;   // row d, col key'

    // staging: waves 0-3 -> K rows [wv*32, +32) (4 gload16).
    // waves 4-7 -> V half (w>>1), dims (w&1)*32 + [0..31] (4 gload16),
    // v4-style per-row chunk swizzle (lq8 ^ lr8).
    int vwave = wv >> 2;
    int w3    = wv & 3;
    const bf16_t* kgp = Kb + (size_t)(wv * 32 + lr8) * HDIM + (lq8 ^ lr8) * 8;
    int vhalf = w3 >> 1, vd0 = (w3 & 1) * 32;
    const bf16_t* vgp = Vb + (size_t)(vd0 + lr8) * SEQ + vhalf * 64
                           + (size_t)((lq8 ^ lr8) * 8);

    auto STAGE = [&](int t, int buf) {
        if (!vwave) {
            const bf16_t* g = kgp + (size_t)t * (128u * HDIM);
            bf16_t* l = &Ks[buf][wv * 32][0];
            gload16(g,             l);
            gload16(g +  8 * HDIM, l +  8 * 64);
            gload16(g + 16 * HDIM, l + 16 * 64);
            gload16(g + 24 * HDIM, l + 24 * 64);
        } else {
            const bf16_t* g = vgp + (size_t)t * 128u;
            bf16_t* l = &Vs[buf][vhalf][vd0][0];
            gload16(g,            l);
            gload16(g +  8 * SEQ, l +  8 * 64);
            gload16(g + 16 * SEQ, l + 16 * 64);
            gload16(g + 24 * SEQ, l + 24 * 64);
        }
    };

    // Q fragments (B-operand: n=q=l16, k=dims), registers for whole kernel
    bf16x8 qf[2];
#pragma unroll
    for (int kk = 0; kk < 2; kk++)
        qf[kk] = *(const bf16x8*)
            &Qb[(size_t)(qw + l16) * HDIM + kk * 32 + quad * 8];

    bf16x8 ones;
#pragma unroll
    for (int i = 0; i < 8; i++) ones[i] = (bf16_t)1.0f;

    floatx4 o_acc[4];
    floatx4 z4  = {0.f, 0.f, 0.f, 0.f};
    floatx4 m16 = {-16.f, -16.f, -16.f, -16.f};
#pragma unroll
    for (int nd = 0; nd < 4; nd++) o_acc[nd] = z4;
    floatx4 l_acc = z4;

    // prologue: stage tile 0 into buffer 0
    STAGE(0, 0);

    for (int t = 0; t < 16; t++) {
        int cur = t & 1;
        drain_dma();       // own DMA complete (incl. prefetch issued last iter)
        __syncthreads();   // buf[cur] fully staged by all waves
        if (t < 15) STAGE(t + 1, cur ^ 1);

        // S^T - 16 = K @ Q^T - 16 : D[key][q], col=l16=q, row=quad*4+r=key
        // half a: keys 0..63 -> st0; half b: keys 64..127 -> st1
        floatx4 st0[4], st1[4];
#pragma unroll
        for (int ns = 0; ns < 4; ns++) { st0[ns] = m16; st1[ns] = m16; }
        __builtin_amdgcn_s_setprio(1);
#pragma unroll
        for (int ns = 0; ns < 4; ns++)
#pragma unroll
            for (int kk = 0; kk < 2; kk++) {
                bf16x8 kf = *(const bf16x8*)
                    &Ks[cur][ns * 16 + l16][(kk * 32 + quad * 8) ^ sw];
                st0[ns] = __builtin_amdgcn_mfma_f32_16x16x32_bf16(
                    kf, qf[kk], st0[ns], 0, 0, 0);
            }
#pragma unroll
        for (int ns = 0; ns < 4; ns++)
#pragma unroll
            for (int kk = 0; kk < 2; kk++) {
                bf16x8 kf = *(const bf16x8*)
                    &Ks[cur][(ns + 4) * 16 + l16][(kk * 32 + quad * 8) ^ sw];
                st1[ns] = __builtin_amdgcn_mfma_f32_16x16x32_bf16(
                    kf, qf[kk], st1[ns], 0, 0, 0);
            }
        __builtin_amdgcn_s_setprio(0);

        // SM(a): P^T = exp2(S^T) keys 0..63, repacked as PV B-operand frags
        bf16x8 pf0[2];
#pragma unroll
        for (int kk = 0; kk < 2; kk++)
#pragma unroll
            for (int tt = 0; tt < 8; tt++)
                pf0[kk][tt] = (bf16_t)__builtin_amdgcn_exp2f(
                    st0[2 * kk + (tt >> 2)][tt & 3]);

        // PV(a): O^T += V^T @ P (keys 0..63); l via ones-MFMA
        __builtin_amdgcn_s_setprio(1);
#pragma unroll
        for (int nd = 0; nd < 4; nd++)
#pragma unroll
            for (int kk = 0; kk < 2; kk++) {
                bf16x8 vf = *(const bf16x8*)
                    &Vs[cur][0][nd * 16 + l16][(kk * 32 + quad * 8) ^ sw];
                o_acc[nd] = __builtin_amdgcn_mfma_f32_16x16x32_bf16(
                    vf, pf0[kk], o_acc[nd], 0, 0, 0);
            }
#pragma unroll
        for (int kk = 0; kk < 2; kk++)
            l_acc = __builtin_amdgcn_mfma_f32_16x16x32_bf16(
                ones, pf0[kk], l_acc, 0, 0, 0);
        __builtin_amdgcn_s_setprio(0);

        // SM(b): keys 64..127 (overlaps PV(a) on the trans/VALU pipes)
        bf16x8 pf1[2];
#pragma unroll
        for (int kk = 0; kk < 2; kk++)
#pragma unroll
            for (int tt = 0; tt < 8; tt++)
                pf1[kk][tt] = (bf16_t)__builtin_amdgcn_exp2f(
                    st1[2 * kk + (tt >> 2)][tt & 3]);

        // PV(b): keys 64..127 (V half 1)
        __builtin_amdgcn_s_setprio(1);
#pragma unroll
        for (int nd = 0; nd < 4; nd++)
#pragma unroll
            for (int kk = 0; kk < 2; kk++) {
                bf16x8 vf = *(const bf16x8*)
                    &Vs[cur][1][nd * 16 + l16][(kk * 32 + quad * 8) ^ sw];
                o_acc[nd] = __builtin_amdgcn_mfma_f32_16x16x32_bf16(
                    vf, pf1[kk], o_acc[nd], 0, 0, 0);
            }
#pragma unroll
        for (int kk = 0; kk < 2; kk++)
            l_acc = __builtin_amdgcn_mfma_f32_16x16x32_bf16(
                ones, pf1[kk], l_acc, 0, 0, 0);
        __builtin_amdgcn_s_setprio(0);
    }

    // l_acc: every reg r of every quad holds the complete l for q = l16.
    float inv = 1.f / l_acc[0];
    int q = qw + l16;
    bf16_t* ob = O + ((size_t)b * SEQ + q) * EMBED + h * HDIM;
#pragma unroll
    for (int nd = 0; nd < 4; nd++)
#pragma unroll
        for (int r = 0; r < 4; r++)
            ob[nd * 16 + quad * 4 + r] = (bf16_t)(o_acc[nd][r] * inv);
}

// ---------------------------------------------------------------------------
// Workspace layout (bytes):
//   [0,  8MB): W^T bf16 (4 x 1M)
//   [8, 16MB): x bf16 [4096,1024]
//   [16,40MB): Q,K bf16 [b,h,s,d] (Q scaled by QSCALE); V slot unused
//   [40,48MB): Vt bf16 [b,h,d,s'] (key-permuted per 64-block, PV-operand map)
//   [48,56MB): attention out bf16 [b,s,h*d]
// ---------------------------------------------------------------------------
extern "C" void kernel_launch(void* const* d_in, const int* in_sizes, int n_in,
                              void* d_out, int out_size, void* d_ws, size_t ws_size,
                              hipStream_t stream)
{
    const float* x  = (const float*)d_in[0];
    const float* wq = (const float*)d_in[1];
    const float* bq = (const float*)d_in[2];
    const float* wk = (const float*)d_in[3];
    const float* bk = (const float*)d_in[4];
    const float* wv = (const float*)d_in[5];
    const float* bv = (const float*)d_in[6];
    const float* wo = (const float*)d_in[7];
    const float* bo = (const float*)d_in[8];

    char*   ws    = (char*)d_ws;
    bf16_t* Wt    = (bf16_t*)ws;                           // 4 x 1048576 bf16
    bf16_t* Xb    = (bf16_t*)(ws + 8ull  * 1024 * 1024);   // 4194304 bf16
    bf16_t* QKV   = (bf16_t*)(ws + 16ull * 1024 * 1024);   // 3 x 4194304 bf16
    bf16_t* Vt    = (bf16_t*)(ws + 40ull * 1024 * 1024);   // 4194304 bf16
    bf16_t* attnO = (bf16_t*)(ws + 48ull * 1024 * 1024);   // 4194304 bf16
    float*  outp  = (float*)d_out;

    // weights transpose + x convert, one launch
    transpose4<<<dim3(32, 32, 8), dim3(32, 8), 0, stream>>>(
        wq, wk, wv, wo, x, Wt, Xb);

    // fused QKV projection: Q/K -> [b,h,s,d]; V -> Vt [b,h,d,s'] directly
    // 1-D grid 768: id%8 = XCD slot, m-major within XCD (B-panel L2 reuse)
    gemm_t<128, 1><<<dim3(768), 256, 0, stream>>>(
        Xb, Wt, bq, bk, bv, QKV, Vt, MTOT, 3072, EMBED);

    attn_mfma<<<dim3(512), 512, 0, stream>>>(
        QKV, QKV + 4194304u, Vt, attnO);

    // output projection: [4096,1024] @ [1024,1024] -> d_out (fp32)
    // BM=64 grid 512 (2 blocks/CU beats BM=128 @ 1 block/CU, per R7)
    gemm_t<64, 0><<<dim3(512), 256, 0, stream>>>(
        attnO, Wt + 3u * 1048576u, bo, bo, bo, outp, nullptr, MTOT, EMBED, EMBED);
}

// Round 11
// 172.325 us; speedup vs baseline: 1.0313x; 1.0134x over previous
//
#include <hip/hip_runtime.h>
#include <cstdint>

typedef __bf16 bf16_t;
typedef __bf16 bf16x4 __attribute__((ext_vector_type(4)));
typedef __bf16 bf16x8 __attribute__((ext_vector_type(8)));
typedef float floatx4 __attribute__((ext_vector_type(4)));

#define EMBED 1024
#define NHEAD 16
#define HDIM  64
#define SEQ   2048
#define BATCH 2
#define MTOT  (BATCH*SEQ)   /* 4096 */
// Q is pre-scaled by 1/sqrt(64) * log2(e) so softmax can use exp2
#define QSCALE 0.18033688011112042f

// async global->LDS, 16B per lane; LDS dest = wave-uniform base + lane*16
__device__ __forceinline__ void gload16(const bf16_t* g, bf16_t* l) {
    __builtin_amdgcn_global_load_lds(
        (const __attribute__((address_space(1))) void*)g,
        (__attribute__((address_space(3))) void*)l, 16, 0, 0);
}

// Explicit drain of the wave's own outstanding LDS-DMA (global_load_lds is
// tracked in vmcnt). __syncthreads() alone is NOT guaranteed to emit
// vmcnt(0) before s_barrier for LDS-DMA ops on every compiler build; the
// 1-deep double-buffer protocol is racy without it (warm-replay failures).
__device__ __forceinline__ void drain_dma() {
    asm volatile("s_waitcnt vmcnt(0)" ::: "memory");
}

// ---------------------------------------------------------------------------
// z<4 : transpose fp32 weight z into bf16 [n][k] (W^T)
// z>=4: straight convert slab z-4 of x fp32 -> bf16
// ---------------------------------------------------------------------------
__global__ __launch_bounds__(256) void transpose4(
    const float* __restrict__ w0, const float* __restrict__ w1,
    const float* __restrict__ w2, const float* __restrict__ w3,
    const float* __restrict__ xin,
    bf16_t* __restrict__ out, bf16_t* __restrict__ xout)
{
    int z = blockIdx.z;
    int tx = threadIdx.x, ty = threadIdx.y;   // block (32,8)
    if (z >= 4) {
        const float* src = xin  + (size_t)(z - 4) * 1048576u;
        bf16_t*      dst = xout + (size_t)(z - 4) * 1048576u;
        int col = blockIdx.x * 32 + tx, rowb = blockIdx.y * 32;
#pragma unroll
        for (int j = 0; j < 4; j++) {
            int rr = rowb + ty + 8 * j;
            dst[(size_t)rr * 1024 + col] = (bf16_t)src[(size_t)rr * 1024 + col];
        }
        return;
    }
    __shared__ float t[32][33];
    const float* src = (z == 0) ? w0 : (z == 1) ? w1 : (z == 2) ? w2 : w3;
    bf16_t* dst = out + (size_t)z * 1048576u;
    int bx = blockIdx.x * 32, by = blockIdx.y * 32;
#pragma unroll
    for (int j = 0; j < 4; j++)
        t[ty + 8 * j][tx] = src[(size_t)(by + ty + 8 * j) * EMBED + bx + tx];
    __syncthreads();
#pragma unroll
    for (int j = 0; j < 4; j++)
        dst[(size_t)(bx + ty + 8 * j) * EMBED + by + tx] = (bf16_t)t[tx][ty + 8 * j];
}

// ---------------------------------------------------------------------------
// MFMA GEMM v2 (R5 champion): global_load_lds DMA staging + LDS DOUBLE-BUFFER
// + one barrier per K-iter (explicit vmcnt(0) drain). XOR chunk swizzle via
// the DMA source address. 1-D grid, XCD swizzle: id%8 = m-group.
// MODE 0: fp32 out row-major.
// MODE 1: fused QKV. Q/K tiles (n0<2048) scatter to bf16 [b,h,s,d] (Q scaled
//         by QSCALE). V tiles (n0>=2048) transpose through LDS and write
//         Vt [b,h,d,s'] with the PV-operand key permutation folded in.
// ---------------------------------------------------------------------------
template<int BM, int MODE>
__global__ __launch_bounds__(256) void gemm_t(
    const bf16_t* __restrict__ A,  const bf16_t* __restrict__ Bt,
    const float* __restrict__ bias0, const float* __restrict__ bias1,
    const float* __restrict__ bias2,
    void* __restrict__ outraw, bf16_t* __restrict__ vtout,
    int M, int N, int K)
{
    constexpr int MS = BM / 32;          // m-subtiles per wave
    constexpr int BUFSZ = (BM + 128) * 64;
    __shared__ __align__(16) bf16_t smem[2 * BUFSZ];

    int tid  = threadIdx.x;
    // XCD-aware decode: id%8 = m-group -> same-XCD blocks share A rows
    int id   = blockIdx.x;
    int c8   = id & 7, rr_ = id >> 3;
    int nblk = N >> 7;
    int n0   = (rr_ % nblk) * 128;
    int m0   = ((rr_ / nblk) * 8 + c8) * BM;
    int wv   = tid >> 6, lane = tid & 63;
    int wr   = wv >> 1,  wc   = wv & 1;
    int quad = lane >> 4, l16 = lane & 15;
    int lr   = lane >> 3, lq = lane & 7;
    int sw   = (l16 & 7) * 8;                    // reader swizzle (elems)
    int lcs  = ((lq ^ lr) * 8);                  // DMA source chunk (elems)

    floatx4 acc[MS][4];
    floatx4 z4 = {0.f, 0.f, 0.f, 0.f};
#pragma unroll
    for (int mi = 0; mi < MS; mi++)
#pragma unroll
        for (int ni = 0; ni < 4; ni++) acc[mi][ni] = z4;

    auto STAGE = [&](int k0, int buf) {
        bf16_t* as = smem + buf * BUFSZ;
        bf16_t* bs = as + BM * 64;
#pragma unroll
        for (int i = 0; i < BM / 32; i++) {
            int r = wv * (BM / 4) + i * 8;
            gload16(&A[(size_t)(m0 + r + lr) * K + k0 + lcs], as + r * 64);
        }
#pragma unroll
        for (int i = 0; i < 4; i++) {
            int r = wv * 32 + i * 8;
            gload16(&Bt[(size_t)(n0 + r + lr) * K + k0 + lcs], bs + r * 64);
        }
    };

    STAGE(0, 0);
    int T = K >> 6;
    for (int t = 0; t < T; t++) {
        int cur = t & 1;
        drain_dma();                     // own DMA (incl. prefetch) complete
        __syncthreads();                 // buf[cur] DMA complete (1-tile cover)
        if (t + 1 < T) STAGE((t + 1) << 6, cur ^ 1);
        bf16_t (*As)[64] = (bf16_t(*)[64])(smem + cur * BUFSZ);
        bf16_t (*Bs)[64] = (bf16_t(*)[64])(smem + cur * BUFSZ + BM * 64);
#pragma unroll
        for (int kk = 0; kk < 2; kk++) {
            bf16x8 af[MS], bfr[4];
            int co = kk * 32 + quad * 8;
#pragma unroll
            for (int i = 0; i < MS; i++)
                af[i]  = *(const bf16x8*)&As[wr * (BM / 2) + i * 16 + l16][co ^ sw];
#pragma unroll
            for (int i = 0; i < 4; i++)
                bfr[i] = *(const bf16x8*)&Bs[wc * 64 + i * 16 + l16][co ^ sw];
#pragma unroll
            for (int mi = 0; mi < MS; mi++)
#pragma unroll
                for (int ni = 0; ni < 4; ni++)
                    acc[mi][ni] = __builtin_amdgcn_mfma_f32_16x16x32_bf16(
                        af[mi], bfr[ni], acc[mi][ni], 0, 0, 0);
        }
    }

    if constexpr (MODE == 1) {
        if (n0 >= 2048) {
            // ------- V tile: LDS transpose + permuted coalesced Vt write ----
            bf16_t (*Ts)[72] = (bf16_t(*)[72])smem;   // 128 hd x 64 s' (+pad)
            int bb = m0 >> 11, s0 = m0 & 2047;
            int hd0 = n0 & 1023;
#pragma unroll
            for (int mh = 0; mh < 2; mh++) {
                __syncthreads();
                if (wr == mh) {
#pragma unroll
                    for (int mi = 0; mi < MS; mi++)
#pragma unroll
                        for (int ni = 0; ni < 4; ni++)
#pragma unroll
                            for (int r = 0; r < 4; r++) {
                                int ml = mi * 16 + quad * 4 + r;     // 0..63
                                int nl = wc * 64 + ni * 16 + l16;    // 0..127
                                float v = acc[mi][ni][r] + bias2[hd0 + nl];
                                int sp = ((ml >> 5) << 5) | (((ml >> 2) & 3) << 3)
                                       | (((ml >> 4) & 1) << 2) | (ml & 3);
                                Ts[nl][sp] = (bf16_t)v;
                            }
                }
                __syncthreads();
#pragma unroll
                for (int i = 0; i < 4; i++) {
                    int c = tid + i * 256;          // 1024 chunk-writes
                    int row = c >> 3, ch = (c & 7) * 8;
                    int hh = row >> 6, dd = row & 63;
                    size_t off = (((size_t)bb * NHEAD + (hd0 >> 6) + hh) * HDIM + dd) * SEQ
                               + (size_t)(s0 + mh * 64 + ch);
                    *(bf16x8*)&vtout[off] = *(const bf16x8*)&Ts[row][ch];
                }
            }
            return;
        }
    }

    // epilogue: C/D layout col = lane&15 (n), row = quad*4 + reg (m)
#pragma unroll
    for (int mi = 0; mi < MS; mi++) {
#pragma unroll
        for (int ni = 0; ni < 4; ni++) {
            int n = n0 + wc * 64 + ni * 16 + l16;
#pragma unroll
            for (int r = 0; r < 4; r++) {
                int m = m0 + wr * (BM / 2) + mi * 16 + quad * 4 + r;
                float v = acc[mi][ni][r];
                if (MODE == 0) {
                    ((float*)outraw)[(size_t)m * N + n] = v + bias0[n];
                } else {
                    int which = n >> 10, cc = n & 1023;   // 0=Q, 1=K here
                    v += (which == 0) ? bias0[cc] : bias1[cc];
                    if (which == 0) v *= QSCALE;
                    int h = cc >> 6, d = cc & 63;
                    int b = m >> 11, s = m & 2047;
                    ((bf16_t*)outraw)[(size_t)which * 4194304u +
                        (((size_t)b * NHEAD + h) * SEQ + s) * HDIM + d] = (bf16_t)v;
                }
            }
        }
    }
}

// ---------------------------------------------------------------------------
// MFMA flash attention v7 (R5 champion):
// S^T-trick, KVBLK=128 (16 iters), V as two half-tiles Vs[buf][half][64][64]
// (verified conflict-free), l via ones-MFMA, half-split QK/SM/PV pipeline,
// DMA double-buffer + explicit vmcnt drain.
// ---------------------------------------------------------------------------
__global__ __launch_bounds__(512, 4) void attn_mfma(
    const bf16_t* __restrict__ Q, const bf16_t* __restrict__ K,
    const bf16_t* __restrict__ Vt, bf16_t* __restrict__ O)
{
    __shared__ __align__(16) bf16_t Ks[2][128][64];     // [buf][key][dim]
    __shared__ __align__(16) bf16_t Vs[2][2][64][64];   // [buf][half][dim][key]

    int tid  = threadIdx.x;
    int wv   = tid >> 6, lane = tid & 63;            // wv 0..7
    int quad = lane >> 4, l16 = lane & 15;
    int sw   = (l16 & 7) * 8;
    int lr8  = lane >> 3, lq8  = lane & 7;           // staging decomp
    int flat = blockIdx.x;
    int hb   = flat & 31;               // head-batch group; XCD = flat%8 = hb%8
    int qt   = flat >> 5;               // q-tile 0..15 (128 rows each)
    int h = hb & 15, b = hb >> 4;
    int bh = b * NHEAD + h;
    int qw = qt * 128 + wv * 16;        // wave's 16 query rows

    const bf16_t* Qb = Q  + (size_t)bh * SEQ * HDIM;
    const bf16_t* Kb = K  + (size_t)bh * SEQ * HDIM;
    const bf16_t* Vb = Vt + (size_t)bh * SEQ * HDIM;   // row d, col key'

    // staging: waves 0-3 -> K rows [wv*32, +32) (4 gload16).
    // waves 4-7 -> V half (w>>1), dims (w&1)*32 + [0..31] (4 gload16),
    // v4-style per-row chunk swizzle (lq8 ^ lr8).
    int vwave = wv >> 2;
    int w3    = wv & 3;
    const bf16_t* kgp = Kb + (size_t)(wv * 32 + lr8) * HDIM + (lq8 ^ lr8) * 8;
    int vhalf = w3 >> 1, vd0 = (w3 & 1) * 32;
    const bf16_t* vgp = Vb + (size_t)(vd0 + lr8) * SEQ + vhalf * 64
                           + (size_t)((lq8 ^ lr8) * 8);

    auto STAGE = [&](int t, int buf) {
        if (!vwave) {
            const bf16_t* g = kgp + (size_t)t * (128u * HDIM);
            bf16_t* l = &Ks[buf][wv * 32][0];
            gload16(g,             l);
            gload16(g +  8 * HDIM, l +  8 * 64);
            gload16(g + 16 * HDIM, l + 16 * 64);
            gload16(g + 24 * HDIM, l + 24 * 64);
        } else {
            const bf16_t* g = vgp + (size_t)t * 128u;
            bf16_t* l = &Vs[buf][vhalf][vd0][0];
            gload16(g,            l);
            gload16(g +  8 * SEQ, l +  8 * 64);
            gload16(g + 16 * SEQ, l + 16 * 64);
            gload16(g + 24 * SEQ, l + 24 * 64);
        }
    };

    // Q fragments (B-operand: n=q=l16, k=dims), registers for whole kernel
    bf16x8 qf[2];
#pragma unroll
    for (int kk = 0; kk < 2; kk++)
        qf[kk] = *(const bf16x8*)
            &Qb[(size_t)(qw + l16) * HDIM + kk * 32 + quad * 8];

    bf16x8 ones;
#pragma unroll
    for (int i = 0; i < 8; i++) ones[i] = (bf16_t)1.0f;

    floatx4 o_acc[4];
    floatx4 z4  = {0.f, 0.f, 0.f, 0.f};
    floatx4 m16 = {-16.f, -16.f, -16.f, -16.f};
#pragma unroll
    for (int nd = 0; nd < 4; nd++) o_acc[nd] = z4;
    floatx4 l_acc = z4;

    // prologue: stage tile 0 into buffer 0
    STAGE(0, 0);

    for (int t = 0; t < 16; t++) {
        int cur = t & 1;
        drain_dma();       // own DMA complete (incl. prefetch issued last iter)
        __syncthreads();   // buf[cur] fully staged by all waves
        if (t < 15) STAGE(t + 1, cur ^ 1);

        // S^T - 16 = K @ Q^T - 16 : D[key][q], col=l16=q, row=quad*4+r=key
        // half a: keys 0..63 -> st0; half b: keys 64..127 -> st1
        floatx4 st0[4], st1[4];
#pragma unroll
        for (int ns = 0; ns < 4; ns++) { st0[ns] = m16; st1[ns] = m16; }
        __builtin_amdgcn_s_setprio(1);
#pragma unroll
        for (int ns = 0; ns < 4; ns++)
#pragma unroll
            for (int kk = 0; kk < 2; kk++) {
                bf16x8 kf = *(const bf16x8*)
                    &Ks[cur][ns * 16 + l16][(kk * 32 + quad * 8) ^ sw];
                st0[ns] = __builtin_amdgcn_mfma_f32_16x16x32_bf16(
                    kf, qf[kk], st0[ns], 0, 0, 0);
            }
#pragma unroll
        for (int ns = 0; ns < 4; ns++)
#pragma unroll
            for (int kk = 0; kk < 2; kk++) {
                bf16x8 kf = *(const bf16x8*)
                    &Ks[cur][(ns + 4) * 16 + l16][(kk * 32 + quad * 8) ^ sw];
                st1[ns] = __builtin_amdgcn_mfma_f32_16x16x32_bf16(
                    kf, qf[kk], st1[ns], 0, 0, 0);
            }
        __builtin_amdgcn_s_setprio(0);

        // SM(a): P^T = exp2(S^T) keys 0..63, repacked as PV B-operand frags
        bf16x8 pf0[2];
#pragma unroll
        for (int kk = 0; kk < 2; kk++)
#pragma unroll
            for (int tt = 0; tt < 8; tt++)
                pf0[kk][tt] = (bf16_t)__builtin_amdgcn_exp2f(
                    st0[2 * kk + (tt >> 2)][tt & 3]);

        // PV(a): O^T += V^T @ P (keys 0..63); l via ones-MFMA
        __builtin_amdgcn_s_setprio(1);
#pragma unroll
        for (int nd = 0; nd < 4; nd++)
#pragma unroll
            for (int kk = 0; kk < 2; kk++) {
                bf16x8 vf = *(const bf16x8*)
                    &Vs[cur][0][nd * 16 + l16][(kk * 32 + quad * 8) ^ sw];
                o_acc[nd] = __builtin_amdgcn_mfma_f32_16x16x32_bf16(
                    vf, pf0[kk], o_acc[nd], 0, 0, 0);
            }
#pragma unroll
        for (int kk = 0; kk < 2; kk++)
            l_acc = __builtin_amdgcn_mfma_f32_16x16x32_bf16(
                ones, pf0[kk], l_acc, 0, 0, 0);
        __builtin_amdgcn_s_setprio(0);

        // SM(b): keys 64..127 (overlaps PV(a) on the trans/VALU pipes)
        bf16x8 pf1[2];
#pragma unroll
        for (int kk = 0; kk < 2; kk++)
#pragma unroll
            for (int tt = 0; tt < 8; tt++)
                pf1[kk][tt] = (bf16_t)__builtin_amdgcn_exp2f(
                    st1[2 * kk + (tt >> 2)][tt & 3]);

        // PV(b): keys 64..127 (V half 1)
        __builtin_amdgcn_s_setprio(1);
#pragma unroll
        for (int nd = 0; nd < 4; nd++)
#pragma unroll
            for (int kk = 0; kk < 2; kk++) {
                bf16x8 vf = *(const bf16x8*)
                    &Vs[cur][1][nd * 16 + l16][(kk * 32 + quad * 8) ^ sw];
                o_acc[nd] = __builtin_amdgcn_mfma_f32_16x16x32_bf16(
                    vf, pf1[kk], o_acc[nd], 0, 0, 0);
            }
#pragma unroll
        for (int kk = 0; kk < 2; kk++)
            l_acc = __builtin_amdgcn_mfma_f32_16x16x32_bf16(
                ones, pf1[kk], l_acc, 0, 0, 0);
        __builtin_amdgcn_s_setprio(0);
    }

    // l_acc: every reg r of every quad holds the complete l for q = l16.
    float inv = 1.f / l_acc[0];
    int q = qw + l16;
    bf16_t* ob = O + ((size_t)b * SEQ + q) * EMBED + h * HDIM;
#pragma unroll
    for (int nd = 0; nd < 4; nd++)
#pragma unroll
        for (int r = 0; r < 4; r++)
            ob[nd * 16 + quad * 4 + r] = (bf16_t)(o_acc[nd][r] * inv);
}

// ---------------------------------------------------------------------------
// Workspace layout (bytes):
//   [0,  8MB): W^T bf16 (4 x 1M)
//   [8, 16MB): x bf16 [4096,1024]
//   [16,40MB): Q,K bf16 [b,h,s,d] (Q scaled by QSCALE); V slot unused
//   [40,48MB): Vt bf16 [b,h,d,s'] (key-permuted per 64-block, PV-operand map)
//   [48,56MB): attention out bf16 [b,s,h*d]
// ---------------------------------------------------------------------------
extern "C" void kernel_launch(void* const* d_in, const int* in_sizes, int n_in,
                              void* d_out, int out_size, void* d_ws, size_t ws_size,
                              hipStream_t stream)
{
    const float* x  = (const float*)d_in[0];
    const float* wq = (const float*)d_in[1];
    const float* bq = (const float*)d_in[2];
    const float* wk = (const float*)d_in[3];
    const float* bk = (const float*)d_in[4];
    const float* wv = (const float*)d_in[5];
    const float* bv = (const float*)d_in[6];
    const float* wo = (const float*)d_in[7];
    const float* bo = (const float*)d_in[8];

    char*   ws    = (char*)d_ws;
    bf16_t* Wt    = (bf16_t*)ws;                           // 4 x 1048576 bf16
    bf16_t* Xb    = (bf16_t*)(ws + 8ull  * 1024 * 1024);   // 4194304 bf16
    bf16_t* QKV   = (bf16_t*)(ws + 16ull * 1024 * 1024);   // 3 x 4194304 bf16
    bf16_t* Vt    = (bf16_t*)(ws + 40ull * 1024 * 1024);   // 4194304 bf16
    bf16_t* attnO = (bf16_t*)(ws + 48ull * 1024 * 1024);   // 4194304 bf16
    float*  outp  = (float*)d_out;

    // weights transpose + x convert, one launch
    transpose4<<<dim3(32, 32, 8), dim3(32, 8), 0, stream>>>(
        wq, wk, wv, wo, x, Wt, Xb);

    // fused QKV projection: Q/K -> [b,h,s,d]; V -> Vt [b,h,d,s'] directly
    // 1-D grid 768: id%8 = m-group (A rows L2-local per XCD)
    gemm_t<128, 1><<<dim3(768), 256, 0, stream>>>(
        Xb, Wt, bq, bk, bv, QKV, Vt, MTOT, 3072, EMBED);

    attn_mfma<<<dim3(512), 512, 0, stream>>>(
        QKV, QKV + 4194304u, Vt, attnO);

    // output projection: [4096,1024] @ [1024,1024] -> d_out (fp32)
    // BM=64 grid 512 (2 blocks/CU beats BM=128 @ 1 block/CU, per R7)
    gemm_t<64, 0><<<dim3(512), 256, 0, stream>>>(
        attnO, Wt + 3u * 1048576u, bo, bo, bo, outp, nullptr, MTOT, EMBED, EMBED);
}